// Round 1
// baseline (572.206 us; speedup 1.0000x reference)
//
#include <hip/hip_runtime.h>
#include <hip/hip_bf16.h>
#include <math.h>

// ---------------------------------------------------------------------------
// BernNet: out = log_softmax( bern_prop( relu(x@W1+b1)@W2+b2 ) )
// bern_prop rewritten in monomial basis: out = sum_j a_j * A^j h  (10 matvecs
// instead of 65). a_j computed on-device from temp; trailing-zero coefficient
// fast-path skips graph work entirely when a_j==0 for all j>=1.
// ---------------------------------------------------------------------------

#define KORD 10

__global__ void coef_kernel(const float* __restrict__ temp,
                            float* __restrict__ acoef,
                            int* __restrict__ flags)
{
    if (threadIdx.x != 0 || blockIdx.x != 0) return;
    // binomial table C[n][k], n,k <= 10
    int C[KORD + 1][KORD + 1];
    for (int n = 0; n <= KORD; ++n) {
        for (int k = 0; k <= KORD; ++k) C[n][k] = 0;
        C[n][0] = 1;
        for (int k = 1; k <= n; ++k)
            C[n][k] = C[n - 1][k - 1] + ((k <= n - 1) ? C[n - 1][k] : 0);
    }
    float a[KORD + 1];
    for (int j = 0; j <= KORD; ++j) a[j] = 0.f;
    for (int m = 0; m <= KORD; ++m) {
        float tm = temp[m];
        tm = tm > 0.f ? tm : 0.f;                       // relu(temp)
        float cm = (float)C[KORD][m] / 1024.0f;         // comb(K,m)/2^K
        // coefficient of x^(p+q) in (1-x)^m (1+x)^(K-m)
        for (int p = 0; p <= m; ++p)
            for (int q = 0; q <= KORD - m; ++q) {
                int Mij = ((p & 1) ? -1 : 1) * C[m][p] * C[KORD - m][q];
                a[p + q] += cm * tm * (float)Mij;
            }
    }
    for (int j = 0; j <= KORD; ++j) acoef[j] = a[j];
    int any = 0;
    for (int j = KORD; j >= 0; --j) {                   // flags[j]: any a_i!=0, i>=j
        if (a[j] != 0.f) any = 1;
        flags[j] = any;
    }
}

__global__ void count_kernel(const int* __restrict__ src, const int* __restrict__ dst,
                             int* __restrict__ degs, int* __restrict__ degd,
                             int E, const int* __restrict__ flags)
{
    if (!flags[1]) return;
    int e = blockIdx.x * 256 + threadIdx.x;
    if (e >= E) return;
    atomicAdd(&degs[src[e]], 1);
    atomicAdd(&degd[dst[e]], 1);
}

__global__ __launch_bounds__(1024) void scan_kernel(const int* __restrict__ degd,
                                                    int* __restrict__ row_ptr,
                                                    int N, const int* __restrict__ flags)
{
    if (!flags[1]) return;
    __shared__ int sums[1024];
    int tid = threadIdx.x;
    int chunk = (N + 1023) / 1024;
    int s0 = tid * chunk;
    int s1 = s0 + chunk; if (s1 > N) s1 = N; if (s0 > N) s0 = N;
    int s = 0;
    for (int i = s0; i < s1; ++i) s += degd[i];
    sums[tid] = s;
    __syncthreads();
    for (int off = 1; off < 1024; off *= 2) {
        int v = (tid >= off) ? sums[tid - off] : 0;
        __syncthreads();
        sums[tid] += v;
        __syncthreads();
    }
    int run = sums[tid] - s;                            // exclusive prefix
    for (int i = s0; i < s1; ++i) { row_ptr[i] = run; run += degd[i]; }
    if (tid == 1023) row_ptr[N] = sums[1023];
}

__global__ void dis_kernel(const int* __restrict__ degs, float* __restrict__ dis,
                           int N, const int* __restrict__ flags)
{
    if (!flags[1]) return;
    int n = blockIdx.x * 256 + threadIdx.x;
    if (n >= N) return;
    int d = degs[n];
    dis[n] = (d > 0) ? rsqrtf((float)d) : 0.f;
}

__global__ void fill_kernel(const int* __restrict__ src, const int* __restrict__ dst,
                            const int* __restrict__ row_ptr, int* __restrict__ cursor,
                            const float* __restrict__ dis,
                            int* __restrict__ csr_src, float* __restrict__ csr_w,
                            int E, const int* __restrict__ flags)
{
    if (!flags[1]) return;
    int e = blockIdx.x * 256 + threadIdx.x;
    if (e >= E) return;
    int s = src[e], d = dst[e];
    int slot = row_ptr[d] + atomicAdd(&cursor[d], 1);
    csr_src[slot] = s;
    csr_w[slot] = dis[s] * dis[d];
}

// h1[N,256] = relu(x[N,512] @ W1[512,256] + b1)
__global__ __launch_bounds__(256) void gemm1_kernel(const float* __restrict__ x,
                                                    const float* __restrict__ W1,
                                                    const float* __restrict__ b1,
                                                    float* __restrict__ h1, int N)
{
    __shared__ __align__(16) float As[16][128];   // [k][row]
    __shared__ __align__(16) float Bs[16][128];   // [k][col]
    int t = threadIdx.x;
    int row0 = blockIdx.x * 128;
    int col0 = blockIdx.y * 128;
    int tx = t & 15, ty = t >> 4;
    float acc[8][8];
#pragma unroll
    for (int i = 0; i < 8; ++i)
#pragma unroll
        for (int j = 0; j < 8; ++j) acc[i][j] = 0.f;

    for (int k0 = 0; k0 < 512; k0 += 16) {
#pragma unroll
        for (int i = 0; i < 2; ++i) {             // A tile: 512 float4 slots
            int slot = t + i * 256;
            int r = slot >> 2, kq = slot & 3;
            float4 av = make_float4(0.f, 0.f, 0.f, 0.f);
            int gr = row0 + r;
            if (gr < N) av = *(const float4*)(x + (long)gr * 512 + k0 + kq * 4);
            As[kq * 4 + 0][r] = av.x;
            As[kq * 4 + 1][r] = av.y;
            As[kq * 4 + 2][r] = av.z;
            As[kq * 4 + 3][r] = av.w;
        }
#pragma unroll
        for (int i = 0; i < 2; ++i) {             // B tile
            int slot = t + i * 256;
            int k = slot >> 5, cq = slot & 31;
            float4 bv = *(const float4*)(W1 + (long)(k0 + k) * 256 + col0 + cq * 4);
            *(float4*)&Bs[k][cq * 4] = bv;
        }
        __syncthreads();
#pragma unroll
        for (int k = 0; k < 16; ++k) {
            float4 a0 = *(float4*)&As[k][ty * 8];
            float4 a1 = *(float4*)&As[k][ty * 8 + 4];
            float4 b0 = *(float4*)&Bs[k][tx * 8];
            float4 b1v = *(float4*)&Bs[k][tx * 8 + 4];
            float av[8] = {a0.x, a0.y, a0.z, a0.w, a1.x, a1.y, a1.z, a1.w};
            float bv[8] = {b0.x, b0.y, b0.z, b0.w, b1v.x, b1v.y, b1v.z, b1v.w};
#pragma unroll
            for (int i = 0; i < 8; ++i)
#pragma unroll
                for (int j = 0; j < 8; ++j) acc[i][j] += av[i] * bv[j];
        }
        __syncthreads();
    }
    float4 bb0 = *(const float4*)(b1 + col0 + tx * 8);
    float4 bb1 = *(const float4*)(b1 + col0 + tx * 8 + 4);
    float bb[8] = {bb0.x, bb0.y, bb0.z, bb0.w, bb1.x, bb1.y, bb1.z, bb1.w};
#pragma unroll
    for (int i = 0; i < 8; ++i) {
        int r = row0 + ty * 8 + i;
        if (r < N) {
            float4 o0, o1;
            o0.x = fmaxf(acc[i][0] + bb[0], 0.f);
            o0.y = fmaxf(acc[i][1] + bb[1], 0.f);
            o0.z = fmaxf(acc[i][2] + bb[2], 0.f);
            o0.w = fmaxf(acc[i][3] + bb[3], 0.f);
            o1.x = fmaxf(acc[i][4] + bb[4], 0.f);
            o1.y = fmaxf(acc[i][5] + bb[5], 0.f);
            o1.z = fmaxf(acc[i][6] + bb[6], 0.f);
            o1.w = fmaxf(acc[i][7] + bb[7], 0.f);
            *(float4*)(h1 + (long)r * 256 + col0 + tx * 8) = o0;
            *(float4*)(h1 + (long)r * 256 + col0 + tx * 8 + 4) = o1;
        }
    }
}

// v0 = h1 @ W2 + b2 ; out = a0 * v0.  16 lanes per 4-node group, 4 classes/lane.
__global__ __launch_bounds__(256) void gemm2_kernel(const float* __restrict__ h1,
                                                    const float* __restrict__ W2,
                                                    const float* __restrict__ b2,
                                                    float* __restrict__ v0,
                                                    float* __restrict__ out,
                                                    const float* __restrict__ acoef, int N)
{
    int t = blockIdx.x * 256 + threadIdx.x;
    int p = t >> 4;             // 4-node group index
    int q = t & 15;             // class quad
    int n0 = p * 4;
    if (n0 >= N) return;
    float a0 = acoef[0];
    float4 acc[4];
#pragma unroll
    for (int u = 0; u < 4; ++u) acc[u] = make_float4(0.f, 0.f, 0.f, 0.f);
    int nn = N - n0; if (nn > 4) nn = 4;

    for (int k = 0; k < 256; k += 4) {
        float4 w4[4];
#pragma unroll
        for (int i = 0; i < 4; ++i) w4[i] = *(const float4*)(W2 + (k + i) * 64 + q * 4);
#pragma unroll
        for (int u = 0; u < 4; ++u) {
            if (u < nn) {
                float4 h4 = *(const float4*)(h1 + (long)(n0 + u) * 256 + k);
                acc[u].x += h4.x * w4[0].x + h4.y * w4[1].x + h4.z * w4[2].x + h4.w * w4[3].x;
                acc[u].y += h4.x * w4[0].y + h4.y * w4[1].y + h4.z * w4[2].y + h4.w * w4[3].y;
                acc[u].z += h4.x * w4[0].z + h4.y * w4[1].z + h4.z * w4[2].z + h4.w * w4[3].z;
                acc[u].w += h4.x * w4[0].w + h4.y * w4[1].w + h4.z * w4[2].w + h4.w * w4[3].w;
            }
        }
    }
    float4 bb = *(const float4*)(b2 + q * 4);
#pragma unroll
    for (int u = 0; u < 4; ++u) {
        if (u < nn) {
            float4 r;
            r.x = acc[u].x + bb.x; r.y = acc[u].y + bb.y;
            r.z = acc[u].z + bb.z; r.w = acc[u].w + bb.w;
            long o = ((long)(n0 + u) << 6) + q * 4;
            *(float4*)(v0 + o) = r;
            float4 ov;
            ov.x = a0 * r.x; ov.y = a0 * r.y; ov.z = a0 * r.z; ov.w = a0 * r.w;
            *(float4*)(out + o) = ov;
        }
    }
}

// vout = A_hat @ vin ; out += a_j * vout.   16 lanes/node, CSR pull, no atomics.
__global__ __launch_bounds__(256) void adj_kernel(const int* __restrict__ row_ptr,
                                                  const int* __restrict__ csr_src,
                                                  const float* __restrict__ csr_w,
                                                  const float* __restrict__ vin,
                                                  float* __restrict__ vout,
                                                  float* __restrict__ out,
                                                  const float* __restrict__ acoef,
                                                  const int* __restrict__ flags,
                                                  int j, int N)
{
    if (!flags[j]) return;                  // all trailing coefficients zero
    int t = blockIdx.x * 256 + threadIdx.x;
    int n = t >> 4;
    if (n >= N) return;
    int q = t & 15;
    int lane = threadIdx.x & 63;
    int grpbase = lane & 48;                // base lane of this 16-lane group
    int beg = row_ptr[n], end = row_ptr[n + 1];
    float4 acc = make_float4(0.f, 0.f, 0.f, 0.f);
    for (int base = beg; base < end; base += 16) {
        int s = 0; float wv = 0.f;
        int idx = base + q;
        if (idx < end) { s = csr_src[idx]; wv = csr_w[idx]; }
        int m = end - base; if (m > 16) m = 16;
        for (int u = 0; u < m; ++u) {
            int ss = __shfl(s, grpbase + u, 64);
            float ww = __shfl(wv, grpbase + u, 64);
            float4 vv = *(const float4*)(vin + ((long)ss << 6) + (q << 2));
            acc.x += ww * vv.x; acc.y += ww * vv.y;
            acc.z += ww * vv.z; acc.w += ww * vv.w;
        }
    }
    long o = ((long)n << 6) + (q << 2);
    *(float4*)(vout + o) = acc;
    float aj = acoef[j];
    float4 ov = *(const float4*)(out + o);
    ov.x += aj * acc.x; ov.y += aj * acc.y;
    ov.z += aj * acc.z; ov.w += aj * acc.w;
    *(float4*)(out + o) = ov;
}

// in-place log_softmax over rows of 64
__global__ __launch_bounds__(256) void lsm_kernel(float* __restrict__ out, int N)
{
    int t = blockIdx.x * 256 + threadIdx.x;
    int n = t >> 6;
    if (n >= N) return;
    int c = t & 63;
    float v = out[(long)n * 64 + c];
    float mx = v;
#pragma unroll
    for (int off = 32; off; off >>= 1) mx = fmaxf(mx, __shfl_xor(mx, off, 64));
    float e = expf(v - mx);
    float s = e;
#pragma unroll
    for (int off = 32; off; off >>= 1) s += __shfl_xor(s, off, 64);
    out[(long)n * 64 + c] = v - mx - logf(s);
}

extern "C" void kernel_launch(void* const* d_in, const int* in_sizes, int n_in,
                              void* d_out, int out_size, void* d_ws, size_t ws_size,
                              hipStream_t stream)
{
    const float* x    = (const float*)d_in[0];
    const int*   ei   = (const int*)d_in[1];
    const float* W1   = (const float*)d_in[2];
    const float* b1   = (const float*)d_in[3];
    const float* W2   = (const float*)d_in[4];
    const float* b2   = (const float*)d_in[5];
    const float* temp = (const float*)d_in[6];

    int N = in_sizes[0] / 512;
    int E = in_sizes[1] / 2;
    const int* src = ei;
    const int* dst = ei + E;
    float* out = (float*)d_out;

    char* w = (char*)d_ws;
    auto alloc = [&](size_t bytes) {
        char* p = w;
        w += (bytes + 255) & ~(size_t)255;
        return p;
    };
    float* acoef  = (float*)alloc(64);
    int*   flags  = (int*)alloc(64);
    int*   degs   = (int*)alloc((size_t)N * 4);
    int*   degd   = (int*)alloc((size_t)N * 4);
    int*   cursor = (int*)alloc((size_t)N * 4);
    int*   rowp   = (int*)alloc((size_t)(N + 1) * 4);
    float* dis    = (float*)alloc((size_t)N * 4);
    int*   csrs   = (int*)alloc((size_t)E * 4);
    float* csrw   = (float*)alloc((size_t)E * 4);
    float* h1     = (float*)alloc((size_t)N * 256 * 4);
    float* v0     = (float*)alloc((size_t)N * 64 * 4);
    float* v1     = (float*)alloc((size_t)N * 64 * 4);

    hipMemsetAsync(degs, 0, (size_t)N * 4, stream);
    hipMemsetAsync(degd, 0, (size_t)N * 4, stream);
    hipMemsetAsync(cursor, 0, (size_t)N * 4, stream);

    coef_kernel<<<1, 64, 0, stream>>>(temp, acoef, flags);

    int eb = (E + 255) / 256;
    count_kernel<<<eb, 256, 0, stream>>>(src, dst, degs, degd, E, flags);
    scan_kernel<<<1, 1024, 0, stream>>>(degd, rowp, N, flags);
    dis_kernel<<<(N + 255) / 256, 256, 0, stream>>>(degs, dis, N, flags);
    fill_kernel<<<eb, 256, 0, stream>>>(src, dst, rowp, cursor, dis, csrs, csrw, E, flags);

    dim3 g1((N + 127) / 128, 2);
    gemm1_kernel<<<g1, 256, 0, stream>>>(x, W1, b1, h1, N);

    int g2 = (((N + 3) / 4) * 16 + 255) / 256;
    gemm2_kernel<<<g2, 256, 0, stream>>>(h1, W2, b2, v0, out, acoef, N);

    float* va = v0;
    float* vb = v1;
    for (int j = 1; j <= KORD; ++j) {
        adj_kernel<<<(N * 16 + 255) / 256, 256, 0, stream>>>(rowp, csrs, csrw, va, vb, out,
                                                             acoef, flags, j, N);
        float* tswap = va; va = vb; vb = tswap;
    }

    lsm_kernel<<<((long)N * 64 + 255) / 256, 256, 0, stream>>>(out, N);
}

// Round 2
// 230.809 us; speedup vs baseline: 2.4791x; 2.4791x over previous
//
#include <hip/hip_runtime.h>
#include <hip/hip_bf16.h>
#include <math.h>

// ---------------------------------------------------------------------------
// BernNet: out = log_softmax( bern_prop( relu(x@W1+b1)@W2+b2 ) )
// bern_prop in monomial basis: out = sum_j a_j A^j v0 (10 matvecs, not 65);
// trailing-zero coefficient fast path skips graph work when a_j==0 for j>=1.
// GEMMs fused into one kernel using bf16x3 split-precision MFMA (hi+lo bf16,
// drop lo*lo) -> fp32-grade accuracy on the 2.5PF matrix pipe.
// ---------------------------------------------------------------------------

#define KORD 10

typedef __attribute__((ext_vector_type(8))) short bf16x8;
typedef __attribute__((ext_vector_type(4))) float f32x4;

static __device__ __forceinline__ ushort f2bf(float f) {
    unsigned u = __float_as_uint(f);
    unsigned r = (u + 0x7fffu + ((u >> 16) & 1u)) >> 16;
    return (ushort)r;
}
static __device__ __forceinline__ float bf2f(ushort h) {
    return __uint_as_float(((unsigned)h) << 16);
}

__global__ void coef_kernel(const float* __restrict__ temp,
                            float* __restrict__ acoef,
                            int* __restrict__ flags)
{
    if (threadIdx.x != 0 || blockIdx.x != 0) return;
    int C[KORD + 1][KORD + 1];
    for (int n = 0; n <= KORD; ++n) {
        for (int k = 0; k <= KORD; ++k) C[n][k] = 0;
        C[n][0] = 1;
        for (int k = 1; k <= n; ++k)
            C[n][k] = C[n - 1][k - 1] + ((k <= n - 1) ? C[n - 1][k] : 0);
    }
    float a[KORD + 1];
    for (int j = 0; j <= KORD; ++j) a[j] = 0.f;
    for (int m = 0; m <= KORD; ++m) {
        float tm = temp[m];
        tm = tm > 0.f ? tm : 0.f;
        float cm = (float)C[KORD][m] / 1024.0f;
        for (int p = 0; p <= m; ++p)
            for (int q = 0; q <= KORD - m; ++q) {
                int Mij = ((p & 1) ? -1 : 1) * C[m][p] * C[KORD - m][q];
                a[p + q] += cm * tm * (float)Mij;
            }
    }
    for (int j = 0; j <= KORD; ++j) acoef[j] = a[j];
    int any = 0;
    for (int j = KORD; j >= 0; --j) {
        if (a[j] != 0.f) any = 1;
        flags[j] = any;
    }
}

// one-time weight conversion: W1 -> k-tiled, col-major-in-tile, XOR-pre-swizzled
// bf16 hi/lo  (tile kt: elems [kt*8192, kt*8192+8192), layout col*32 + swz(q)*8 + j)
// W2 -> [col][k] k-contig bf16 hi/lo
__global__ void prep_kernel(const float* __restrict__ W1, const float* __restrict__ W2,
                            ushort* __restrict__ w1h, ushort* __restrict__ w1l,
                            ushort* __restrict__ w2h, ushort* __restrict__ w2l)
{
    int tid = blockIdx.x * 256 + threadIdx.x;
    if (tid < 512 * 256) {
        int qj  = tid & 31;           // k within 32-tile
        int col = (tid >> 5) & 255;
        int kt  = tid >> 13;          // 0..15
        int k = kt * 32 + qj;
        float v = W1[k * 256 + col];
        ushort hi = f2bf(v);
        ushort lo = f2bf(v - bf2f(hi));
        int q = qj >> 3, j = qj & 7;
        int idx = kt * 8192 + col * 32 + ((q ^ (col & 3)) << 3) + j;
        w1h[idx] = hi; w1l[idx] = lo;
    } else {
        int t2 = tid - 512 * 256;
        if (t2 < 256 * 64) {
            int col = t2 >> 8, k = t2 & 255;
            float v = W2[k * 64 + col];
            ushort hi = f2bf(v);
            ushort lo = f2bf(v - bf2f(hi));
            w2h[col * 256 + k] = hi; w2l[col * 256 + k] = lo;
        }
    }
}

// ---- graph preprocessing (early-exits when all a_j==0 for j>=1) ------------
__global__ void count_kernel(const int* __restrict__ src, const int* __restrict__ dst,
                             int* __restrict__ degs, int* __restrict__ degd,
                             int E, const int* __restrict__ flags)
{
    if (!flags[1]) return;
    int e = blockIdx.x * 256 + threadIdx.x;
    if (e >= E) return;
    atomicAdd(&degs[src[e]], 1);
    atomicAdd(&degd[dst[e]], 1);
}

__global__ __launch_bounds__(1024) void scan_kernel(const int* __restrict__ degd,
                                                    int* __restrict__ row_ptr,
                                                    int N, const int* __restrict__ flags)
{
    if (!flags[1]) return;
    __shared__ int sums[1024];
    int tid = threadIdx.x;
    int chunk = (N + 1023) / 1024;
    int s0 = tid * chunk;
    int s1 = s0 + chunk; if (s1 > N) s1 = N; if (s0 > N) s0 = N;
    int s = 0;
    for (int i = s0; i < s1; ++i) s += degd[i];
    sums[tid] = s;
    __syncthreads();
    for (int off = 1; off < 1024; off *= 2) {
        int v = (tid >= off) ? sums[tid - off] : 0;
        __syncthreads();
        sums[tid] += v;
        __syncthreads();
    }
    int run = sums[tid] - s;
    for (int i = s0; i < s1; ++i) { row_ptr[i] = run; run += degd[i]; }
    if (tid == 1023) row_ptr[N] = sums[1023];
}

__global__ void dis_kernel(const int* __restrict__ degs, float* __restrict__ dis,
                           int N, const int* __restrict__ flags)
{
    if (!flags[1]) return;
    int n = blockIdx.x * 256 + threadIdx.x;
    if (n >= N) return;
    int d = degs[n];
    dis[n] = (d > 0) ? rsqrtf((float)d) : 0.f;
}

__global__ void fill_kernel(const int* __restrict__ src, const int* __restrict__ dst,
                            const int* __restrict__ row_ptr, int* __restrict__ cursor,
                            const float* __restrict__ dis,
                            int* __restrict__ csr_src, float* __restrict__ csr_w,
                            int E, const int* __restrict__ flags)
{
    if (!flags[1]) return;
    int e = blockIdx.x * 256 + threadIdx.x;
    if (e >= E) return;
    int s = src[e], d = dst[e];
    int slot = row_ptr[d] + atomicAdd(&cursor[d], 1);
    csr_src[slot] = s;
    csr_w[slot] = dis[s] * dis[d];
}

// ---- fused MLP: v0 = relu(x@W1+b1)@W2+b2 ; out = a0*v0 --------------------
// block: 512 thr (8 waves), 128 rows. phase1: 128x256, K=512, waves 2x4
// (64x64/wave). phase2: 128x64, K=256, 16 rows/wave. bf16x3 products.
__global__ __launch_bounds__(512) void gemm_fused(
    const float* __restrict__ x,
    const ushort* __restrict__ w1h, const ushort* __restrict__ w1l,
    const ushort* __restrict__ w2h, const ushort* __restrict__ w2l,
    const float* __restrict__ b1, const float* __restrict__ b2,
    float* __restrict__ v0, float* __restrict__ out,
    const float* __restrict__ acoef, int N)
{
    __shared__ __align__(16) char smraw[65536];
    ushort* xh = (ushort*)smraw;              //  8KB  128x32 bf16 (swz)
    ushort* xl = (ushort*)(smraw + 8192);     //  8KB
    ushort* bh = (ushort*)(smraw + 16384);    // 16KB  256x32 bf16 (swz)
    ushort* bl = (ushort*)(smraw + 32768);    // 16KB
    ushort* h1 = (ushort*)smraw;              // 64KB  128x256 bf16 (swz) [reuse]

    const int t   = threadIdx.x;
    const int lane = t & 63;
    const int wid = t >> 6;        // 0..7
    const int wm  = wid >> 2;      // 0..1
    const int wn  = wid & 3;       // 0..3
    const int l15 = lane & 15;
    const int lg  = lane >> 4;     // 0..3
    const int row0 = blockIdx.x * 128;

    f32x4 acc[4][4];
#pragma unroll
    for (int i = 0; i < 4; ++i)
#pragma unroll
        for (int j = 0; j < 4; ++j) acc[i][j] = (f32x4)0.f;

    // x staging geometry: thread -> (row sr, 8-float quad sq)
    const int sr = t >> 2;
    const int sq = t & 3;
    const bool xvalid = (row0 + sr) < N;
    const float* xsrc = x + (size_t)(row0 + sr) * 512 + sq * 8;
    const int xdst = sr * 32 + ((sq ^ (sr & 3)) << 3);   // ushort idx, pre-swizzled

    for (int kt = 0; kt < 16; ++kt) {
        __syncthreads();
        // --- stage x tile (fp32 -> hi/lo bf16, swizzled) ---
        float4 a0 = make_float4(0.f, 0.f, 0.f, 0.f), a1 = a0;
        if (xvalid) {
            a0 = *(const float4*)(xsrc + kt * 32);
            a1 = *(const float4*)(xsrc + kt * 32 + 4);
        }
        float vv[8] = {a0.x, a0.y, a0.z, a0.w, a1.x, a1.y, a1.z, a1.w};
        ushort hh[8], ll[8];
#pragma unroll
        for (int j = 0; j < 8; ++j) {
            hh[j] = f2bf(vv[j]);
            ll[j] = f2bf(vv[j] - bf2f(hh[j]));
        }
        uint4 hp, lp;
        hp.x = hh[0] | (hh[1] << 16); hp.y = hh[2] | (hh[3] << 16);
        hp.z = hh[4] | (hh[5] << 16); hp.w = hh[6] | (hh[7] << 16);
        lp.x = ll[0] | (ll[1] << 16); lp.y = ll[2] | (ll[3] << 16);
        lp.z = ll[4] | (ll[5] << 16); lp.w = ll[6] | (ll[7] << 16);
        *(uint4*)&xh[xdst] = hp;
        *(uint4*)&xl[xdst] = lp;
        // --- stage W1 tile (pre-swizzled in global: straight copy) ---
        {
            const uint4* gh = (const uint4*)(w1h + kt * 8192);
            const uint4* gl = (const uint4*)(w1l + kt * 8192);
            uint4* dh = (uint4*)bh;
            uint4* dl = (uint4*)bl;
            uint4 v0h = gh[t], v1h = gh[t + 512];
            uint4 v0l = gl[t], v1l = gl[t + 512];
            dh[t] = v0h; dh[t + 512] = v1h;
            dl[t] = v0l; dl[t + 512] = v1l;
        }
        __syncthreads();
        // --- fragments + MFMA ---
        bf16x8 Ah[4], Al[4];
#pragma unroll
        for (int mf = 0; mf < 4; ++mf) {
            int row = wm * 64 + mf * 16 + l15;
            int ai = row * 32 + ((lg ^ (row & 3)) << 3);
            Ah[mf] = *(const bf16x8*)&xh[ai];
            Al[mf] = *(const bf16x8*)&xl[ai];
        }
#pragma unroll
        for (int nf = 0; nf < 4; ++nf) {
            int col = wn * 64 + nf * 16 + l15;
            int bi = col * 32 + ((lg ^ (col & 3)) << 3);
            bf16x8 Bh = *(const bf16x8*)&bh[bi];
            bf16x8 Bl = *(const bf16x8*)&bl[bi];
#pragma unroll
            for (int mf = 0; mf < 4; ++mf) {
                acc[mf][nf] = __builtin_amdgcn_mfma_f32_16x16x32_bf16(Ah[mf], Bh, acc[mf][nf], 0, 0, 0);
                acc[mf][nf] = __builtin_amdgcn_mfma_f32_16x16x32_bf16(Ah[mf], Bl, acc[mf][nf], 0, 0, 0);
                acc[mf][nf] = __builtin_amdgcn_mfma_f32_16x16x32_bf16(Al[mf], Bh, acc[mf][nf], 0, 0, 0);
            }
        }
    }
    __syncthreads();
    // --- h1 = relu(acc + b1) -> bf16 -> LDS (swizzled [128][256]) ---
#pragma unroll
    for (int nf = 0; nf < 4; ++nf) {
        int col = wn * 64 + nf * 16 + l15;
        float bb = b1[col];
        int sl = col >> 3;
#pragma unroll
        for (int mf = 0; mf < 4; ++mf) {
#pragma unroll
            for (int r = 0; r < 4; ++r) {
                int row = wm * 64 + mf * 16 + lg * 4 + r;
                float v = acc[mf][nf][r] + bb;
                v = fmaxf(v, 0.f);
                h1[row * 256 + ((sl ^ (row & 7)) << 3) + (col & 7)] = f2bf(v);
            }
        }
    }
    __syncthreads();
    // --- phase 2: rows wid*16..+15, all 64 cols, K=256 ---
    f32x4 acc2[4];
#pragma unroll
    for (int i = 0; i < 4; ++i) acc2[i] = (f32x4)0.f;
#pragma unroll
    for (int ks = 0; ks < 8; ++ks) {
        int row = wid * 16 + l15;
        int sl = ks * 4 + lg;
        bf16x8 A = *(const bf16x8*)&h1[row * 256 + ((sl ^ (row & 7)) << 3)];
#pragma unroll
        for (int nf = 0; nf < 4; ++nf) {
            int col = nf * 16 + l15;
            int k = ks * 32 + lg * 8;
            bf16x8 Bh = *(const bf16x8*)(w2h + col * 256 + k);
            bf16x8 Bl = *(const bf16x8*)(w2l + col * 256 + k);
            acc2[nf] = __builtin_amdgcn_mfma_f32_16x16x32_bf16(A, Bh, acc2[nf], 0, 0, 0);
            acc2[nf] = __builtin_amdgcn_mfma_f32_16x16x32_bf16(A, Bl, acc2[nf], 0, 0, 0);
        }
    }
    float a0c = acoef[0];
#pragma unroll
    for (int nf = 0; nf < 4; ++nf) {
        int col = nf * 16 + l15;
        float bb = b2[col];
#pragma unroll
        for (int r = 0; r < 4; ++r) {
            int row = row0 + wid * 16 + lg * 4 + r;
            if (row < N) {
                float v = acc2[nf][r] + bb;
                size_t o = (size_t)row * 64 + col;
                v0[o] = v;
                out[o] = a0c * v;
            }
        }
    }
}

// vout = A_hat @ vin ; out += a_j * vout.   16 lanes/node, CSR pull.
__global__ __launch_bounds__(256) void adj_kernel(const int* __restrict__ row_ptr,
                                                  const int* __restrict__ csr_src,
                                                  const float* __restrict__ csr_w,
                                                  const float* __restrict__ vin,
                                                  float* __restrict__ vout,
                                                  float* __restrict__ out,
                                                  const float* __restrict__ acoef,
                                                  const int* __restrict__ flags,
                                                  int j, int N)
{
    if (!flags[j]) return;
    int t = blockIdx.x * 256 + threadIdx.x;
    int n = t >> 4;
    if (n >= N) return;
    int q = t & 15;
    int lane = threadIdx.x & 63;
    int grpbase = lane & 48;
    int beg = row_ptr[n], end = row_ptr[n + 1];
    float4 acc = make_float4(0.f, 0.f, 0.f, 0.f);
    for (int base = beg; base < end; base += 16) {
        int s = 0; float wv = 0.f;
        int idx = base + q;
        if (idx < end) { s = csr_src[idx]; wv = csr_w[idx]; }
        int m = end - base; if (m > 16) m = 16;
        for (int u = 0; u < m; ++u) {
            int ss = __shfl(s, grpbase + u, 64);
            float ww = __shfl(wv, grpbase + u, 64);
            float4 vv = *(const float4*)(vin + ((long)ss << 6) + (q << 2));
            acc.x += ww * vv.x; acc.y += ww * vv.y;
            acc.z += ww * vv.z; acc.w += ww * vv.w;
        }
    }
    long o = ((long)n << 6) + (q << 2);
    *(float4*)(vout + o) = acc;
    float aj = acoef[j];
    float4 ov = *(const float4*)(out + o);
    ov.x += aj * acc.x; ov.y += aj * acc.y;
    ov.z += aj * acc.z; ov.w += aj * acc.w;
    *(float4*)(out + o) = ov;
}

__global__ __launch_bounds__(256) void lsm_kernel(float* __restrict__ out, int N)
{
    int t = blockIdx.x * 256 + threadIdx.x;
    int n = t >> 6;
    if (n >= N) return;
    int c = t & 63;
    float v = out[(long)n * 64 + c];
    float mx = v;
#pragma unroll
    for (int off = 32; off; off >>= 1) mx = fmaxf(mx, __shfl_xor(mx, off, 64));
    float e = expf(v - mx);
    float s = e;
#pragma unroll
    for (int off = 32; off; off >>= 1) s += __shfl_xor(s, off, 64);
    out[(long)n * 64 + c] = v - mx - logf(s);
}

extern "C" void kernel_launch(void* const* d_in, const int* in_sizes, int n_in,
                              void* d_out, int out_size, void* d_ws, size_t ws_size,
                              hipStream_t stream)
{
    const float* x    = (const float*)d_in[0];
    const int*   ei   = (const int*)d_in[1];
    const float* W1   = (const float*)d_in[2];
    const float* b1   = (const float*)d_in[3];
    const float* W2   = (const float*)d_in[4];
    const float* b2   = (const float*)d_in[5];
    const float* temp = (const float*)d_in[6];

    int N = in_sizes[0] / 512;
    int E = in_sizes[1] / 2;
    const int* src = ei;
    const int* dst = ei + E;
    float* out = (float*)d_out;

    char* w = (char*)d_ws;
    auto alloc = [&](size_t bytes) {
        char* p = w;
        w += (bytes + 255) & ~(size_t)255;
        return p;
    };
    float* acoef  = (float*)alloc(64);
    int*   flags  = (int*)alloc(64);
    int*   degs   = (int*)alloc((size_t)N * 4);
    int*   degd   = (int*)alloc((size_t)N * 4);
    int*   cursor = (int*)alloc((size_t)N * 4);
    int*   rowp   = (int*)alloc((size_t)(N + 1) * 4);
    float* dis    = (float*)alloc((size_t)N * 4);
    int*   csrs   = (int*)alloc((size_t)E * 4);
    float* csrw   = (float*)alloc((size_t)E * 4);
    ushort* w1h   = (ushort*)alloc(512 * 256 * 2);
    ushort* w1l   = (ushort*)alloc(512 * 256 * 2);
    ushort* w2h   = (ushort*)alloc(256 * 64 * 2);
    ushort* w2l   = (ushort*)alloc(256 * 64 * 2);
    float* v0     = (float*)alloc((size_t)N * 64 * 4);
    float* v1     = (float*)alloc((size_t)N * 64 * 4);

    hipMemsetAsync(degs, 0, (size_t)N * 4, stream);
    hipMemsetAsync(degd, 0, (size_t)N * 4, stream);
    hipMemsetAsync(cursor, 0, (size_t)N * 4, stream);

    coef_kernel<<<1, 64, 0, stream>>>(temp, acoef, flags);
    prep_kernel<<<576, 256, 0, stream>>>(W1, W2, w1h, w1l, w2h, w2l);

    int eb = (E + 255) / 256;
    count_kernel<<<eb, 256, 0, stream>>>(src, dst, degs, degd, E, flags);
    scan_kernel<<<1, 1024, 0, stream>>>(degd, rowp, N, flags);
    dis_kernel<<<(N + 255) / 256, 256, 0, stream>>>(degs, dis, N, flags);
    fill_kernel<<<eb, 256, 0, stream>>>(src, dst, rowp, cursor, dis, csrs, csrw, E, flags);

    int gb = (N + 127) / 128;
    gemm_fused<<<gb, 512, 0, stream>>>(x, w1h, w1l, w2h, w2l, b1, b2, v0, out, acoef, N);

    float* va = v0;
    float* vb = v1;
    for (int j = 1; j <= KORD; ++j) {
        adj_kernel<<<(N * 16 + 255) / 256, 256, 0, stream>>>(rowp, csrs, csrw, va, vb, out,
                                                             acoef, flags, j, N);
        float* tswap = va; va = vb; vb = tswap;
    }

    lsm_kernel<<<((long)N * 64 + 255) / 256, 256, 0, stream>>>(out, N);
}

// Round 3
// 224.349 us; speedup vs baseline: 2.5505x; 1.0288x over previous
//
#include <hip/hip_runtime.h>
#include <hip/hip_bf16.h>
#include <math.h>

// ---------------------------------------------------------------------------
// BernNet: out = log_softmax( bern_prop( relu(x@W1+b1)@W2+b2 ) )
// bern_prop in monomial basis: out = sum_j a_j A^j v0 (10 matvecs, not 65);
// trailing-zero coefficient fast path skips graph work when a_j==0 for j>=1,
// and fuses log_softmax into the GEMM epilogue in that case.
// GEMMs: bf16x3 split-precision MFMA. W1/W2 fragments pre-arranged in global
// (lane-contiguous) and loaded straight to VGPRs from L2; x double-buffered
// through LDS with issue-early/write-late staging, 1 barrier per K-tile.
// ---------------------------------------------------------------------------

#define KORD 10

typedef __attribute__((ext_vector_type(8))) short bf16x8;
typedef __attribute__((ext_vector_type(4))) float f32x4;

static __device__ __forceinline__ ushort f2bf(float f) {   // RNE (weights, h1)
    unsigned u = __float_as_uint(f);
    unsigned r = (u + 0x7fffu + ((u >> 16) & 1u)) >> 16;
    return (ushort)r;
}
static __device__ __forceinline__ float bf2f(ushort h) {
    return __uint_as_float(((unsigned)h) << 16);
}

__global__ void coef_kernel(const float* __restrict__ temp,
                            float* __restrict__ acoef,
                            int* __restrict__ flags)
{
    if (threadIdx.x != 0 || blockIdx.x != 0) return;
    int C[KORD + 1][KORD + 1];
    for (int n = 0; n <= KORD; ++n) {
        for (int k = 0; k <= KORD; ++k) C[n][k] = 0;
        C[n][0] = 1;
        for (int k = 1; k <= n; ++k)
            C[n][k] = C[n - 1][k - 1] + ((k <= n - 1) ? C[n - 1][k] : 0);
    }
    float a[KORD + 1];
    for (int j = 0; j <= KORD; ++j) a[j] = 0.f;
    for (int m = 0; m <= KORD; ++m) {
        float tm = temp[m];
        tm = tm > 0.f ? tm : 0.f;
        float cm = (float)C[KORD][m] / 1024.0f;
        for (int p = 0; p <= m; ++p)
            for (int q = 0; q <= KORD - m; ++q) {
                int Mij = ((p & 1) ? -1 : 1) * C[m][p] * C[KORD - m][q];
                a[p + q] += cm * tm * (float)Mij;
            }
    }
    for (int j = 0; j <= KORD; ++j) acoef[j] = a[j];
    int any = 0;
    for (int j = KORD; j >= 0; --j) {
        if (a[j] != 0.f) any = 1;
        flags[j] = any;
    }
}

// Weight conversion to lane-contiguous fragment layout (hi/lo bf16):
// W1: idx = kt*8192 + col*32 + lg*8 + j   (k = kt*32+lg*8+j, col in [0,256))
// W2: idx = ks*2048 + col*32 + lg*8 + j   (k = ks*32+lg*8+j, col in [0,64))
// => a wave's 16x16x32 B-fragment (16 cols x 4 lg x 8) is 1KB contiguous.
__global__ void prep_kernel(const float* __restrict__ W1, const float* __restrict__ W2,
                            ushort* __restrict__ w1h, ushort* __restrict__ w1l,
                            ushort* __restrict__ w2h, ushort* __restrict__ w2l)
{
    int tid = blockIdx.x * 256 + threadIdx.x;
    if (tid < 512 * 256) {
        int j = tid & 7, lg = (tid >> 3) & 3, col = (tid >> 5) & 255, kt = tid >> 13;
        int k = kt * 32 + lg * 8 + j;
        float v = W1[k * 256 + col];
        ushort hi = f2bf(v);
        ushort lo = f2bf(v - bf2f(hi));
        w1h[tid] = hi; w1l[tid] = lo;
    } else {
        int t2 = tid - 512 * 256;
        if (t2 < 256 * 64) {
            int j = t2 & 7, lg = (t2 >> 3) & 3, col = (t2 >> 5) & 63, ks = t2 >> 11;
            int k = ks * 32 + lg * 8 + j;
            float v = W2[k * 64 + col];
            ushort hi = f2bf(v);
            ushort lo = f2bf(v - bf2f(hi));
            w2h[t2] = hi; w2l[t2] = lo;
        }
    }
}

// ---- graph preprocessing (early-exits when all a_j==0 for j>=1) ------------
__global__ void count_kernel(const int* __restrict__ src, const int* __restrict__ dst,
                             int* __restrict__ degs, int* __restrict__ degd,
                             int E, const int* __restrict__ flags)
{
    if (!flags[1]) return;
    int e = blockIdx.x * 256 + threadIdx.x;
    if (e >= E) return;
    atomicAdd(&degs[src[e]], 1);
    atomicAdd(&degd[dst[e]], 1);
}

__global__ __launch_bounds__(1024) void scan_kernel(const int* __restrict__ degd,
                                                    int* __restrict__ row_ptr,
                                                    int N, const int* __restrict__ flags)
{
    if (!flags[1]) return;
    __shared__ int sums[1024];
    int tid = threadIdx.x;
    int chunk = (N + 1023) / 1024;
    int s0 = tid * chunk;
    int s1 = s0 + chunk; if (s1 > N) s1 = N; if (s0 > N) s0 = N;
    int s = 0;
    for (int i = s0; i < s1; ++i) s += degd[i];
    sums[tid] = s;
    __syncthreads();
    for (int off = 1; off < 1024; off *= 2) {
        int v = (tid >= off) ? sums[tid - off] : 0;
        __syncthreads();
        sums[tid] += v;
        __syncthreads();
    }
    int run = sums[tid] - s;
    for (int i = s0; i < s1; ++i) { row_ptr[i] = run; run += degd[i]; }
    if (tid == 1023) row_ptr[N] = sums[1023];
}

__global__ void dis_kernel(const int* __restrict__ degs, float* __restrict__ dis,
                           int N, const int* __restrict__ flags)
{
    if (!flags[1]) return;
    int n = blockIdx.x * 256 + threadIdx.x;
    if (n >= N) return;
    int d = degs[n];
    dis[n] = (d > 0) ? rsqrtf((float)d) : 0.f;
}

__global__ void fill_kernel(const int* __restrict__ src, const int* __restrict__ dst,
                            const int* __restrict__ row_ptr, int* __restrict__ cursor,
                            const float* __restrict__ dis,
                            int* __restrict__ csr_src, float* __restrict__ csr_w,
                            int E, const int* __restrict__ flags)
{
    if (!flags[1]) return;
    int e = blockIdx.x * 256 + threadIdx.x;
    if (e >= E) return;
    int s = src[e], d = dst[e];
    int slot = row_ptr[d] + atomicAdd(&cursor[d], 1);
    csr_src[slot] = s;
    csr_w[slot] = dis[s] * dis[d];
}

// ---- fused MLP: v0 = relu(x@W1+b1)@W2+b2 ; out = a0*v0 (or lsm(v0)) -------
__global__ __launch_bounds__(512, 4) void gemm_fused(
    const float* __restrict__ x,
    const ushort* __restrict__ w1h, const ushort* __restrict__ w1l,
    const ushort* __restrict__ w2h, const ushort* __restrict__ w2l,
    const float* __restrict__ b1, const float* __restrict__ b2,
    float* __restrict__ v0, float* __restrict__ out,
    const float* __restrict__ acoef, const int* __restrict__ flags, int N)
{
    __shared__ __align__(16) char smraw[65536];
    ushort* xh0 = (ushort*)smraw;                 // 8KB 128x32 bf16 hi (swz)
    ushort* xl0 = (ushort*)(smraw + 8192);
    ushort* xh1 = (ushort*)(smraw + 16384);
    ushort* xl1 = (ushort*)(smraw + 24576);
    ushort* h1  = (ushort*)smraw;                 // 64KB 128x256 bf16 (swz)

    const int t    = threadIdx.x;
    const int lane = t & 63;
    const int wid  = t >> 6;
    const int wm   = wid >> 2;
    const int wn   = wid & 3;
    const int l15  = lane & 15;
    const int lg   = lane >> 4;
    const int row0 = blockIdx.x * 128;

    f32x4 acc[4][4];
#pragma unroll
    for (int i = 0; i < 4; ++i)
#pragma unroll
        for (int j = 0; j < 4; ++j) acc[i][j] = (f32x4)0.f;

    // x staging geometry: thread -> (row sr, 8-elem quad sq)
    const int sr = t >> 2;
    const int sq = t & 3;
    const bool xvalid = (row0 + sr) < N;
    const float* xsrc = x + (size_t)(row0 + sr) * 512 + sq * 8;
    const int xdst = sr * 32 + ((sq ^ (sr & 3)) << 3);

    auto convert_write = [&](ushort* dh, ushort* dl, const float* xa) {
        uint ah[4], al[4];
#pragma unroll
        for (int p = 0; p < 4; ++p) {
            uint u0 = __float_as_uint(xa[2 * p]);
            uint u1 = __float_as_uint(xa[2 * p + 1]);
            uint h0 = u0 & 0xffff0000u;
            uint h1b = u1 & 0xffff0000u;
            ah[p] = (u0 >> 16) | h1b;
            float l0 = xa[2 * p]     - __uint_as_float(h0);   // exact residual
            float l1 = xa[2 * p + 1] - __uint_as_float(h1b);
            al[p] = (__float_as_uint(l0) >> 16) | (__float_as_uint(l1) & 0xffff0000u);
        }
        *(uint4*)&dh[xdst] = make_uint4(ah[0], ah[1], ah[2], ah[3]);
        *(uint4*)&dl[xdst] = make_uint4(al[0], al[1], al[2], al[3]);
    };

    // prologue: stage kt=0
    {
        float xa[8] = {0, 0, 0, 0, 0, 0, 0, 0};
        if (xvalid) {
            float4 a = *(const float4*)(xsrc);
            float4 b = *(const float4*)(xsrc + 4);
            xa[0] = a.x; xa[1] = a.y; xa[2] = a.z; xa[3] = a.w;
            xa[4] = b.x; xa[5] = b.y; xa[6] = b.z; xa[7] = b.w;
        }
        convert_write(xh0, xl0, xa);
    }
    __syncthreads();

    auto mfma_kt = [&](int kt, const ushort* ch, const ushort* cl,
                       ushort* nh, ushort* nl, bool last) {
        float xa[8] = {0, 0, 0, 0, 0, 0, 0, 0};
        if (!last && xvalid) {                       // issue next-tile loads EARLY
            float4 a = *(const float4*)(xsrc + (kt + 1) * 32);
            float4 b = *(const float4*)(xsrc + (kt + 1) * 32 + 4);
            xa[0] = a.x; xa[1] = a.y; xa[2] = a.z; xa[3] = a.w;
            xa[4] = b.x; xa[5] = b.y; xa[6] = b.z; xa[7] = b.w;
        }
        bf16x8 Ah[4];
#pragma unroll
        for (int mf = 0; mf < 4; ++mf) {
            int row = wm * 64 + mf * 16 + l15;
            int ai = row * 32 + ((lg ^ (row & 3)) << 3);
            Ah[mf] = *(const bf16x8*)&ch[ai];
        }
#pragma unroll
        for (int nf = 0; nf < 4; ++nf) {
            size_t bo = (size_t)kt * 8192 + wn * 2048 + nf * 512 + (l15 << 5) + (lg << 3);
            bf16x8 Bh = *(const bf16x8*)(w1h + bo);
            bf16x8 Bl = *(const bf16x8*)(w1l + bo);
#pragma unroll
            for (int mf = 0; mf < 4; ++mf)
                acc[mf][nf] = __builtin_amdgcn_mfma_f32_16x16x32_bf16(Ah[mf], Bh, acc[mf][nf], 0, 0, 0);
#pragma unroll
            for (int mf = 0; mf < 4; ++mf)
                acc[mf][nf] = __builtin_amdgcn_mfma_f32_16x16x32_bf16(Ah[mf], Bl, acc[mf][nf], 0, 0, 0);
#pragma unroll
            for (int mf = 0; mf < 4; ++mf) {
                int row = wm * 64 + mf * 16 + l15;
                int ai = row * 32 + ((lg ^ (row & 3)) << 3);
                bf16x8 Alm = *(const bf16x8*)&cl[ai];
                acc[mf][nf] = __builtin_amdgcn_mfma_f32_16x16x32_bf16(Alm, Bh, acc[mf][nf], 0, 0, 0);
            }
        }
        if (!last) convert_write(nh, nl, xa);        // vmcnt lands here, post-MFMA
        __syncthreads();                             // single barrier per K-tile
    };

    for (int kt = 0; kt < 16; kt += 2) {
        mfma_kt(kt,     xh0, xl0, xh1, xl1, false);
        mfma_kt(kt + 1, xh1, xl1, xh0, xl0, kt + 1 == 15);
    }

    // --- h1 = relu(acc + b1) -> bf16 -> LDS (swizzled [128][256]) ---
#pragma unroll
    for (int nf = 0; nf < 4; ++nf) {
        int col = wn * 64 + nf * 16 + l15;
        float bb = b1[col];
        int sl = col >> 3;
#pragma unroll
        for (int mf = 0; mf < 4; ++mf) {
#pragma unroll
            for (int r = 0; r < 4; ++r) {
                int row = wm * 64 + mf * 16 + lg * 4 + r;
                float v = acc[mf][nf][r] + bb;
                v = fmaxf(v, 0.f);
                h1[row * 256 + ((sl ^ (row & 7)) << 3) + (col & 7)] = f2bf(v);
            }
        }
    }
    __syncthreads();

    // --- phase 2: rows wid*16..+15, 64 cols, K=256, bf16x2 (h1 single) ---
    f32x4 acc2[4];
#pragma unroll
    for (int i = 0; i < 4; ++i) acc2[i] = (f32x4)0.f;
#pragma unroll
    for (int ks = 0; ks < 8; ++ks) {
        int row = wid * 16 + l15;
        int sl = ks * 4 + lg;
        bf16x8 A = *(const bf16x8*)&h1[row * 256 + ((sl ^ (row & 7)) << 3)];
#pragma unroll
        for (int nf = 0; nf < 4; ++nf) {
            size_t bo = (size_t)ks * 2048 + (nf * 16 + l15) * 32 + (lg << 3);
            bf16x8 Bh = *(const bf16x8*)(w2h + bo);
            bf16x8 Bl = *(const bf16x8*)(w2l + bo);
            acc2[nf] = __builtin_amdgcn_mfma_f32_16x16x32_bf16(A, Bh, acc2[nf], 0, 0, 0);
            acc2[nf] = __builtin_amdgcn_mfma_f32_16x16x32_bf16(A, Bl, acc2[nf], 0, 0, 0);
        }
    }

    // --- epilogue ---
    int flag1 = flags[1];
    float a0c = acoef[0];
    float z[4][4];
#pragma unroll
    for (int nf = 0; nf < 4; ++nf) {
        float bb = b2[nf * 16 + l15];
#pragma unroll
        for (int r = 0; r < 4; ++r) z[nf][r] = acc2[nf][r] + bb;
    }
    if (!flag1) {
        // fused log_softmax: row is shared by the 16 l15-lanes of this lg group
#pragma unroll
        for (int r = 0; r < 4; ++r) {
            int row = row0 + wid * 16 + lg * 4 + r;
            float mx = fmaxf(fmaxf(z[0][r], z[1][r]), fmaxf(z[2][r], z[3][r]));
#pragma unroll
            for (int off = 1; off < 16; off <<= 1) mx = fmaxf(mx, __shfl_xor(mx, off, 64));
            float s = expf(z[0][r] - mx) + expf(z[1][r] - mx)
                    + expf(z[2][r] - mx) + expf(z[3][r] - mx);
#pragma unroll
            for (int off = 1; off < 16; off <<= 1) s += __shfl_xor(s, off, 64);
            float lns = logf(s);
            if (row < N) {
#pragma unroll
                for (int nf = 0; nf < 4; ++nf)
                    out[(size_t)row * 64 + nf * 16 + l15] = z[nf][r] - mx - lns;
            }
        }
    } else {
#pragma unroll
        for (int nf = 0; nf < 4; ++nf) {
            int col = nf * 16 + l15;
#pragma unroll
            for (int r = 0; r < 4; ++r) {
                int row = row0 + wid * 16 + lg * 4 + r;
                if (row < N) {
                    size_t o = (size_t)row * 64 + col;
                    v0[o] = z[nf][r];
                    out[o] = a0c * z[nf][r];
                }
            }
        }
    }
}

// vout = A_hat @ vin ; out += a_j * vout.   16 lanes/node, CSR pull.
__global__ __launch_bounds__(256) void adj_kernel(const int* __restrict__ row_ptr,
                                                  const int* __restrict__ csr_src,
                                                  const float* __restrict__ csr_w,
                                                  const float* __restrict__ vin,
                                                  float* __restrict__ vout,
                                                  float* __restrict__ out,
                                                  const float* __restrict__ acoef,
                                                  const int* __restrict__ flags,
                                                  int j, int N)
{
    if (!flags[j]) return;
    int t = blockIdx.x * 256 + threadIdx.x;
    int n = t >> 4;
    if (n >= N) return;
    int q = t & 15;
    int lane = threadIdx.x & 63;
    int grpbase = lane & 48;
    int beg = row_ptr[n], end = row_ptr[n + 1];
    float4 acc = make_float4(0.f, 0.f, 0.f, 0.f);
    for (int base = beg; base < end; base += 16) {
        int s = 0; float wv = 0.f;
        int idx = base + q;
        if (idx < end) { s = csr_src[idx]; wv = csr_w[idx]; }
        int m = end - base; if (m > 16) m = 16;
        for (int u = 0; u < m; ++u) {
            int ss = __shfl(s, grpbase + u, 64);
            float ww = __shfl(wv, grpbase + u, 64);
            float4 vv = *(const float4*)(vin + ((long)ss << 6) + (q << 2));
            acc.x += ww * vv.x; acc.y += ww * vv.y;
            acc.z += ww * vv.z; acc.w += ww * vv.w;
        }
    }
    long o = ((long)n << 6) + (q << 2);
    *(float4*)(vout + o) = acc;
    float aj = acoef[j];
    float4 ov = *(const float4*)(out + o);
    ov.x += aj * acc.x; ov.y += aj * acc.y;
    ov.z += aj * acc.z; ov.w += aj * acc.w;
    *(float4*)(out + o) = ov;
}

// log_softmax pass, only needed when propagation ran (flags[1] != 0)
__global__ __launch_bounds__(256) void lsm_kernel(float* __restrict__ out, int N,
                                                  const int* __restrict__ flags)
{
    if (!flags[1]) return;
    int t = blockIdx.x * 256 + threadIdx.x;
    int n = t >> 6;
    if (n >= N) return;
    int c = t & 63;
    float v = out[(long)n * 64 + c];
    float mx = v;
#pragma unroll
    for (int off = 32; off; off >>= 1) mx = fmaxf(mx, __shfl_xor(mx, off, 64));
    float e = expf(v - mx);
    float s = e;
#pragma unroll
    for (int off = 32; off; off >>= 1) s += __shfl_xor(s, off, 64);
    out[(long)n * 64 + c] = v - mx - logf(s);
}

extern "C" void kernel_launch(void* const* d_in, const int* in_sizes, int n_in,
                              void* d_out, int out_size, void* d_ws, size_t ws_size,
                              hipStream_t stream)
{
    const float* x    = (const float*)d_in[0];
    const int*   ei   = (const int*)d_in[1];
    const float* W1   = (const float*)d_in[2];
    const float* b1   = (const float*)d_in[3];
    const float* W2   = (const float*)d_in[4];
    const float* b2   = (const float*)d_in[5];
    const float* temp = (const float*)d_in[6];

    int N = in_sizes[0] / 512;
    int E = in_sizes[1] / 2;
    const int* src = ei;
    const int* dst = ei + E;
    float* out = (float*)d_out;

    char* w = (char*)d_ws;
    auto alloc = [&](size_t bytes) {
        char* p = w;
        w += (bytes + 255) & ~(size_t)255;
        return p;
    };
    float* acoef  = (float*)alloc(64);
    int*   flags  = (int*)alloc(64);
    int*   degs   = (int*)alloc((size_t)N * 4);
    int*   degd   = (int*)alloc((size_t)N * 4);
    int*   cursor = (int*)alloc((size_t)N * 4);
    int*   rowp   = (int*)alloc((size_t)(N + 1) * 4);
    float* dis    = (float*)alloc((size_t)N * 4);
    int*   csrs   = (int*)alloc((size_t)E * 4);
    float* csrw   = (float*)alloc((size_t)E * 4);
    ushort* w1h   = (ushort*)alloc(512 * 256 * 2);
    ushort* w1l   = (ushort*)alloc(512 * 256 * 2);
    ushort* w2h   = (ushort*)alloc(256 * 64 * 2);
    ushort* w2l   = (ushort*)alloc(256 * 64 * 2);
    float* v0     = (float*)alloc((size_t)N * 64 * 4);
    float* v1     = (float*)alloc((size_t)N * 64 * 4);

    hipMemsetAsync(degs, 0, (size_t)N * 4, stream);
    hipMemsetAsync(degd, 0, (size_t)N * 4, stream);
    hipMemsetAsync(cursor, 0, (size_t)N * 4, stream);

    coef_kernel<<<1, 64, 0, stream>>>(temp, acoef, flags);
    prep_kernel<<<576, 256, 0, stream>>>(W1, W2, w1h, w1l, w2h, w2l);

    int eb = (E + 255) / 256;
    count_kernel<<<eb, 256, 0, stream>>>(src, dst, degs, degd, E, flags);
    scan_kernel<<<1, 1024, 0, stream>>>(degd, rowp, N, flags);
    dis_kernel<<<(N + 255) / 256, 256, 0, stream>>>(degs, dis, N, flags);
    fill_kernel<<<eb, 256, 0, stream>>>(src, dst, rowp, cursor, dis, csrs, csrw, E, flags);

    int gb = (N + 127) / 128;
    gemm_fused<<<gb, 512, 0, stream>>>(x, w1h, w1l, w2h, w2l, b1, b2, v0, out,
                                       acoef, flags, N);

    float* va = v0;
    float* vb = v1;
    for (int j = 1; j <= KORD; ++j) {
        adj_kernel<<<(N * 16 + 255) / 256, 256, 0, stream>>>(rowp, csrs, csrw, va, vb, out,
                                                             acoef, flags, j, N);
        float* tswap = va; va = vb; vb = tswap;
    }

    lsm_kernel<<<((long)N * 64 + 255) / 256, 256, 0, stream>>>(out, N, flags);
}

// Round 5
// 147.703 us; speedup vs baseline: 3.8740x; 1.5189x over previous
//
#include <hip/hip_runtime.h>
#include <hip/hip_bf16.h>
#include <math.h>

// ---------------------------------------------------------------------------
// BernNet: out = log_softmax( bern_prop( relu(x@W1+b1)@W2+b2 ) )
// bern_prop in monomial basis: out = sum_j a_j A^j v0 (10 matvecs, not 65);
// trailing-zero coefficient fast path skips graph work when a_j==0 for j>=1
// and fuses log_softmax into the phase-2 epilogue.
// Phase 1: h1 = relu(x@W1+b1) as bf16 (single-pass bf16 MFMA; W1-bf16 error
// is dominated by h1-bf16 storage error already present in passing rounds).
// Phase 2: v0 = h1@W2h + h1@W2l + b2 (split-precision W2).
// ---------------------------------------------------------------------------

#define KORD 10

typedef __attribute__((ext_vector_type(8))) short bf16x8;
typedef __attribute__((ext_vector_type(4))) float f32x4;

typedef __attribute__((address_space(1))) const unsigned int* gas_t;
typedef __attribute__((address_space(3))) unsigned int* las_t;

static __device__ __forceinline__ void gll16(const void* g, void* l) {
    // per-lane global addr g; wave-uniform LDS base l; writes l + lane*16
    __builtin_amdgcn_global_load_lds((gas_t)g, (las_t)l, 16, 0, 0);
}

static __device__ __forceinline__ ushort f2bf(float f) {   // RNE
    unsigned u = __float_as_uint(f);
    unsigned r = (u + 0x7fffu + ((u >> 16) & 1u)) >> 16;
    return (ushort)r;
}
static __device__ __forceinline__ float bf2f(ushort h) {
    return __uint_as_float(((unsigned)h) << 16);
}
static __device__ __forceinline__ uint pack2(float a, float b) {
    return (uint)f2bf(a) | ((uint)f2bf(b) << 16);
}

__global__ void coef_kernel(const float* __restrict__ temp,
                            float* __restrict__ acoef,
                            int* __restrict__ flags)
{
    if (threadIdx.x != 0 || blockIdx.x != 0) return;
    int C[KORD + 1][KORD + 1];
    for (int n = 0; n <= KORD; ++n) {
        for (int k = 0; k <= KORD; ++k) C[n][k] = 0;
        C[n][0] = 1;
        for (int k = 1; k <= n; ++k)
            C[n][k] = C[n - 1][k - 1] + ((k <= n - 1) ? C[n - 1][k] : 0);
    }
    float a[KORD + 1];
    for (int j = 0; j <= KORD; ++j) a[j] = 0.f;
    for (int m = 0; m <= KORD; ++m) {
        float tm = temp[m];
        tm = tm > 0.f ? tm : 0.f;
        float cm = (float)C[KORD][m] / 1024.0f;
        for (int p = 0; p <= m; ++p)
            for (int q = 0; q <= KORD - m; ++q) {
                int Mij = ((p & 1) ? -1 : 1) * C[m][p] * C[KORD - m][q];
                a[p + q] += cm * tm * (float)Mij;
            }
    }
    for (int j = 0; j <= KORD; ++j) acoef[j] = a[j];
    int any = 0;
    for (int j = KORD; j >= 0; --j) {
        if (a[j] != 0.f) any = 1;
        flags[j] = any;
    }
}

// W1 -> fragment-linear bf16: idx = kt*8192 + col*32 + lg*8 + j  (k=kt*32+lg*8+j)
// W2 -> hi/lo bf16:           idx = ks*2048 + col*32 + lg*8 + j  (k=ks*32+lg*8+j)
__global__ void prep_kernel(const float* __restrict__ W1, const float* __restrict__ W2,
                            ushort* __restrict__ w1b,
                            ushort* __restrict__ w2h, ushort* __restrict__ w2l)
{
    int tid = blockIdx.x * 256 + threadIdx.x;
    if (tid < 512 * 256) {
        int j = tid & 7, lg = (tid >> 3) & 3, col = (tid >> 5) & 255, kt = tid >> 13;
        int k = kt * 32 + lg * 8 + j;
        w1b[tid] = f2bf(W1[k * 256 + col]);
    } else {
        int t2 = tid - 512 * 256;
        if (t2 < 256 * 64) {
            int j = t2 & 7, lg = (t2 >> 3) & 3, col = (t2 >> 5) & 63, ks = t2 >> 11;
            int k = ks * 32 + lg * 8 + j;
            float v = W2[k * 64 + col];
            ushort hi = f2bf(v);
            ushort lo = f2bf(v - bf2f(hi));
            w2h[t2] = hi; w2l[t2] = lo;
        }
    }
}

// ---- graph preprocessing (early-exits when all a_j==0 for j>=1) ------------
__global__ void count_kernel(const int* __restrict__ src, const int* __restrict__ dst,
                             int* __restrict__ degs, int* __restrict__ degd,
                             int E, const int* __restrict__ flags)
{
    if (!flags[1]) return;
    int stride = gridDim.x * 256;
    for (int e = blockIdx.x * 256 + threadIdx.x; e < E; e += stride) {
        atomicAdd(&degs[src[e]], 1);
        atomicAdd(&degd[dst[e]], 1);
    }
}

__global__ __launch_bounds__(1024) void scan_kernel(const int* __restrict__ degd,
                                                    int* __restrict__ row_ptr,
                                                    int N, const int* __restrict__ flags)
{
    if (!flags[1]) return;
    __shared__ int sums[1024];
    int tid = threadIdx.x;
    int chunk = (N + 1023) / 1024;
    int s0 = tid * chunk;
    int s1 = s0 + chunk; if (s1 > N) s1 = N; if (s0 > N) s0 = N;
    int s = 0;
    for (int i = s0; i < s1; ++i) s += degd[i];
    sums[tid] = s;
    __syncthreads();
    for (int off = 1; off < 1024; off *= 2) {
        int v = (tid >= off) ? sums[tid - off] : 0;
        __syncthreads();
        sums[tid] += v;
        __syncthreads();
    }
    int run = sums[tid] - s;
    for (int i = s0; i < s1; ++i) { row_ptr[i] = run; run += degd[i]; }
    if (tid == 1023) row_ptr[N] = sums[1023];
}

__global__ void dis_kernel(const int* __restrict__ degs, float* __restrict__ dis,
                           int N, const int* __restrict__ flags)
{
    if (!flags[1]) return;
    int stride = gridDim.x * 256;
    for (int n = blockIdx.x * 256 + threadIdx.x; n < N; n += stride) {
        int d = degs[n];
        dis[n] = (d > 0) ? rsqrtf((float)d) : 0.f;
    }
}

__global__ void fill_kernel(const int* __restrict__ src, const int* __restrict__ dst,
                            const int* __restrict__ row_ptr, int* __restrict__ cursor,
                            const float* __restrict__ dis,
                            int* __restrict__ csr_src, float* __restrict__ csr_w,
                            int E, const int* __restrict__ flags)
{
    if (!flags[1]) return;
    int stride = gridDim.x * 256;
    for (int e = blockIdx.x * 256 + threadIdx.x; e < E; e += stride) {
        int s = src[e], d = dst[e];
        int slot = row_ptr[d] + atomicAdd(&cursor[d], 1);
        csr_src[slot] = s;
        csr_w[slot] = dis[s] * dis[d];
    }
}

// ---- phase 1: h1 = relu(x@W1+b1) -> bf16, fragment-linear global ----------
// 256 thr / 4 waves; tile 64 rows x 256 cols; waves 2x2 (32 rows x 128 cols).
// LDS: x dbuf 2x4KB (frag-linear), W1 dbuf 2x16KB via global_load_lds.
__global__ __launch_bounds__(256, 4) void gemm1_kernel(
    const float* __restrict__ x,
    const ushort* __restrict__ w1b,
    const float* __restrict__ b1,
    ushort* __restrict__ h1g, int N)
{
    __shared__ __align__(16) char sm[40960];
    // [0:4K) xbuf0, [4K:8K) xbuf1, [8K:24K) Bbuf0, [24K:40K) Bbuf1; h1 reuses [0:32K)

    const int t    = threadIdx.x;
    const int lane = t & 63;
    const int wv   = t >> 6;        // wave 0..3
    const int wm   = wv >> 1;       // row half
    const int wn   = wv & 1;        // col half
    const int l15  = lane & 15;
    const int lg   = lane >> 4;
    const int tile = blockIdx.x;
    const int row0 = tile * 64;

    f32x4 acc[2][8];
#pragma unroll
    for (int i = 0; i < 2; ++i)
#pragma unroll
        for (int j = 0; j < 8; ++j) acc[i][j] = (f32x4)0.f;

    // x load geometry: thread -> (local row sr = t>>2, quad sq = t&3)
    const int sr = t >> 2;
    const int sq = t & 3;
    int rl = row0 + sr; if (rl > N - 1) rl = N - 1;       // clamp (no OOB)
    const float* xsrc = x + (size_t)rl * 512 + sq * 8;
    ushort* xb0 = (ushort*)sm;
    ushort* xb1 = (ushort*)(sm + 4096);
    // frag-linear x dest: idx8 = (sr>>4)*64 + (sr&15)*4 + sq  == t
    uint4* xdst0 = (uint4*)(sm + t * 16);
    uint4* xdst1 = (uint4*)(sm + 4096 + t * 16);

    // W1 gll: wave wv stages 4KB of the 16KB kt-tile
    const char* w1base = (const char*)w1b;               // byte view
    char* bb0 = sm + 8192;
    char* bb1 = sm + 24576;

    // ---- prologue ----
    float4 xa0 = *(const float4*)(xsrc);
    float4 xa1 = *(const float4*)(xsrc + 4);
    {
#pragma unroll
        for (int i = 0; i < 4; ++i)
            gll16(w1base + (size_t)wv * 4096 + i * 1024 + lane * 16,
                  bb0 + wv * 4096 + i * 1024);
    }
    float4 xb0r = *(const float4*)(xsrc + 32);
    float4 xb1r = *(const float4*)(xsrc + 36);
    *xdst0 = make_uint4(pack2(xa0.x, xa0.y), pack2(xa0.z, xa0.w),
                        pack2(xa1.x, xa1.y), pack2(xa1.z, xa1.w));
    __syncthreads();

    for (int kt2 = 0; kt2 < 16; kt2 += 2) {
        // ================= sub-iter A: kt = kt2 (cur buf 0) =================
        {
            int ktn = kt2 + 1;                            // stage W1 for kt+1
#pragma unroll
            for (int i = 0; i < 4; ++i)
                gll16(w1base + (size_t)ktn * 16384 + wv * 4096 + i * 1024 + lane * 16,
                      bb1 + wv * 4096 + i * 1024);
            int ktx = kt2 + 2; if (ktx > 15) ktx = 15;    // x prefetch depth 2
            xa0 = *(const float4*)(xsrc + ktx * 32);
            xa1 = *(const float4*)(xsrc + ktx * 32 + 4);

            bf16x8 A0 = *(const bf16x8*)&xb0[((wm * 2 + 0) * 64 + l15 * 4 + lg) * 8];
            bf16x8 A1 = *(const bf16x8*)&xb0[((wm * 2 + 1) * 64 + l15 * 4 + lg) * 8];
#pragma unroll
            for (int nf = 0; nf < 8; ++nf) {
                bf16x8 B = *(const bf16x8*)(bb0 + ((wn * 8 + nf) * 64 + l15 * 4 + lg) * 16);
                acc[0][nf] = __builtin_amdgcn_mfma_f32_16x16x32_bf16(A0, B, acc[0][nf], 0, 0, 0);
                acc[1][nf] = __builtin_amdgcn_mfma_f32_16x16x32_bf16(A1, B, acc[1][nf], 0, 0, 0);
            }
            // write x(kt+1) to xbuf1
            *xdst1 = make_uint4(pack2(xb0r.x, xb0r.y), pack2(xb0r.z, xb0r.w),
                                pack2(xb1r.x, xb1r.y), pack2(xb1r.z, xb1r.w));
            __syncthreads();
        }
        // ================= sub-iter B: kt = kt2+1 (cur buf 1) ===============
        {
            int ktn = kt2 + 2; if (ktn > 15) ktn = 15;    // stage W1 for kt+2
#pragma unroll
            for (int i = 0; i < 4; ++i)
                gll16(w1base + (size_t)ktn * 16384 + wv * 4096 + i * 1024 + lane * 16,
                      bb0 + wv * 4096 + i * 1024);
            int ktx = kt2 + 3; if (ktx > 15) ktx = 15;
            xb0r = *(const float4*)(xsrc + ktx * 32);
            xb1r = *(const float4*)(xsrc + ktx * 32 + 4);

            bf16x8 A0 = *(const bf16x8*)&xb1[((wm * 2 + 0) * 64 + l15 * 4 + lg) * 8];
            bf16x8 A1 = *(const bf16x8*)&xb1[((wm * 2 + 1) * 64 + l15 * 4 + lg) * 8];
#pragma unroll
            for (int nf = 0; nf < 8; ++nf) {
                bf16x8 B = *(const bf16x8*)(bb1 + ((wn * 8 + nf) * 64 + l15 * 4 + lg) * 16);
                acc[0][nf] = __builtin_amdgcn_mfma_f32_16x16x32_bf16(A0, B, acc[0][nf], 0, 0, 0);
                acc[1][nf] = __builtin_amdgcn_mfma_f32_16x16x32_bf16(A1, B, acc[1][nf], 0, 0, 0);
            }
            *xdst0 = make_uint4(pack2(xa0.x, xa0.y), pack2(xa0.z, xa0.w),
                                pack2(xa1.x, xa1.y), pack2(xa1.z, xa1.w));
            __syncthreads();
        }
    }

    // ---- epilogue: relu(acc+b1) -> bf16 -> LDS (frag-linear) -> global ----
    ushort* h1l = (ushort*)sm;                            // 32KB tile image
#pragma unroll
    for (int mf = 0; mf < 2; ++mf) {
        int g = wm * 2 + mf;
#pragma unroll
        for (int nf = 0; nf < 8; ++nf) {
            int col = wn * 128 + nf * 16 + l15;
            float bb = b1[col];
            int ks = col >> 5, lgw = (col >> 3) & 3, j = col & 7;
#pragma unroll
            for (int r = 0; r < 4; ++r) {
                float v = acc[mf][nf][r] + bb;
                v = fmaxf(v, 0.f);
                int l15w = lg * 4 + r;
                h1l[(ks * 256 + g * 64 + l15w * 4 + lgw) * 8 + j] = f2bf(v);
            }
        }
    }
    __syncthreads();
    {
        uint4* gdst = (uint4*)((char*)h1g + (size_t)tile * 32768);
        const uint4* lsrc = (const uint4*)sm;
#pragma unroll
        for (int i = 0; i < 8; ++i)
            gdst[t * 8 + i] = lsrc[t * 8 + i];
    }
}

// ---- phase 2: v0 = h1@W2 + b2 ; out = a0*v0 (or fused log_softmax) --------
// 256 thr / 4 waves; tile 64 rows; wave = 16 rows x 64 cols; K=256 from LDS.
__global__ __launch_bounds__(256, 4) void gemm2_kernel(
    const ushort* __restrict__ h1g,
    const ushort* __restrict__ w2h, const ushort* __restrict__ w2l,
    const float* __restrict__ b2,
    float* __restrict__ v0, float* __restrict__ out,
    const float* __restrict__ acoef, const int* __restrict__ flags, int N)
{
    __shared__ __align__(16) char sm[32768];
    const int t    = threadIdx.x;
    const int lane = t & 63;
    const int wv   = t >> 6;
    const int l15  = lane & 15;
    const int lg   = lane >> 4;
    const int tile = blockIdx.x;

    // stage h1 tile (32KB, frag-linear image) via global_load_lds
    const char* gsrc = (const char*)h1g + (size_t)tile * 32768;
#pragma unroll
    for (int i = 0; i < 8; ++i)
        gll16(gsrc + (size_t)wv * 8192 + i * 1024 + lane * 16,
              sm + wv * 8192 + i * 1024);
    __syncthreads();

    const ushort* h1l = (const ushort*)sm;
    f32x4 acc2[4];
#pragma unroll
    for (int i = 0; i < 4; ++i) acc2[i] = (f32x4)0.f;

#pragma unroll
    for (int ks = 0; ks < 8; ++ks) {
        bf16x8 A = *(const bf16x8*)&h1l[(ks * 256 + wv * 64 + l15 * 4 + lg) * 8];
#pragma unroll
        for (int nf = 0; nf < 4; ++nf) {
            size_t bo = (size_t)ks * 2048 + (nf * 16 + l15) * 32 + (lg << 3);
            bf16x8 Bh = *(const bf16x8*)(w2h + bo);
            bf16x8 Bl = *(const bf16x8*)(w2l + bo);
            acc2[nf] = __builtin_amdgcn_mfma_f32_16x16x32_bf16(A, Bh, acc2[nf], 0, 0, 0);
            acc2[nf] = __builtin_amdgcn_mfma_f32_16x16x32_bf16(A, Bl, acc2[nf], 0, 0, 0);
        }
    }

    int flag1 = flags[1];
    float a0c = acoef[0];
    float z[4][4];
#pragma unroll
    for (int nf = 0; nf < 4; ++nf) {
        float bb = b2[nf * 16 + l15];
#pragma unroll
        for (int r = 0; r < 4; ++r) z[nf][r] = acc2[nf][r] + bb;
    }
    if (!flag1) {
        // fused log_softmax: the 16 l15-lanes of this lg group share 4 rows
#pragma unroll
        for (int r = 0; r < 4; ++r) {
            int row = tile * 64 + wv * 16 + lg * 4 + r;
            float mx = fmaxf(fmaxf(z[0][r], z[1][r]), fmaxf(z[2][r], z[3][r]));
#pragma unroll
            for (int off = 1; off < 16; off <<= 1) mx = fmaxf(mx, __shfl_xor(mx, off, 64));
            float s = expf(z[0][r] - mx) + expf(z[1][r] - mx)
                    + expf(z[2][r] - mx) + expf(z[3][r] - mx);
#pragma unroll
            for (int off = 1; off < 16; off <<= 1) s += __shfl_xor(s, off, 64);
            float lns = logf(s);
            if (row < N) {
#pragma unroll
                for (int nf = 0; nf < 4; ++nf)
                    out[(size_t)row * 64 + nf * 16 + l15] = z[nf][r] - mx - lns;
            }
        }
    } else {
#pragma unroll
        for (int nf = 0; nf < 4; ++nf) {
            int col = nf * 16 + l15;
#pragma unroll
            for (int r = 0; r < 4; ++r) {
                int row = tile * 64 + wv * 16 + lg * 4 + r;
                if (row < N) {
                    size_t o = (size_t)row * 64 + col;
                    v0[o] = z[nf][r];
                    out[o] = a0c * z[nf][r];
                }
            }
        }
    }
}

// vout = A_hat @ vin ; out += a_j * vout.  16 lanes/node, CSR pull.
__global__ __launch_bounds__(256) void adj_kernel(const int* __restrict__ row_ptr,
                                                  const int* __restrict__ csr_src,
                                                  const float* __restrict__ csr_w,
                                                  const float* __restrict__ vin,
                                                  float* __restrict__ vout,
                                                  float* __restrict__ out,
                                                  const float* __restrict__ acoef,
                                                  const int* __restrict__ flags,
                                                  int j, int N)
{
    if (!flags[j]) return;
    float aj = acoef[j];
    int stride = gridDim.x * 256;
    for (int t = blockIdx.x * 256 + threadIdx.x; t < N * 16; t += stride) {
        int n = t >> 4;
        int q = t & 15;
        int lane = threadIdx.x & 63;
        int grpbase = lane & 48;
        int beg = row_ptr[n], end = row_ptr[n + 1];
        float4 acc = make_float4(0.f, 0.f, 0.f, 0.f);
        for (int base = beg; base < end; base += 16) {
            int s = 0; float wvv = 0.f;
            int idx = base + q;
            if (idx < end) { s = csr_src[idx]; wvv = csr_w[idx]; }
            int m = end - base; if (m > 16) m = 16;
            for (int u = 0; u < m; ++u) {
                int ss = __shfl(s, grpbase + u, 64);
                float ww = __shfl(wvv, grpbase + u, 64);
                float4 vv = *(const float4*)(vin + ((long)ss << 6) + (q << 2));
                acc.x += ww * vv.x; acc.y += ww * vv.y;
                acc.z += ww * vv.z; acc.w += ww * vv.w;
            }
        }
        long o = ((long)n << 6) + (q << 2);
        *(float4*)(vout + o) = acc;
        float4 ov = *(const float4*)(out + o);
        ov.x += aj * acc.x; ov.y += aj * acc.y;
        ov.z += aj * acc.z; ov.w += aj * acc.w;
        *(float4*)(out + o) = ov;
    }
}

// standalone log_softmax, only when propagation ran
__global__ __launch_bounds__(256) void lsm_kernel(float* __restrict__ out, int N,
                                                  const int* __restrict__ flags)
{
    if (!flags[1]) return;
    int stride = gridDim.x * 256;
    for (int t = blockIdx.x * 256 + threadIdx.x; t < N * 64; t += stride) {
        int n = t >> 6;
        int c = t & 63;
        float v = out[(long)n * 64 + c];
        float mx = v;
#pragma unroll
        for (int off = 32; off; off >>= 1) mx = fmaxf(mx, __shfl_xor(mx, off, 64));
        float e = expf(v - mx);
        float s = e;
#pragma unroll
        for (int off = 32; off; off >>= 1) s += __shfl_xor(s, off, 64);
        out[(long)n * 64 + c] = v - mx - logf(s);
    }
}

extern "C" void kernel_launch(void* const* d_in, const int* in_sizes, int n_in,
                              void* d_out, int out_size, void* d_ws, size_t ws_size,
                              hipStream_t stream)
{
    const float* x    = (const float*)d_in[0];
    const int*   ei   = (const int*)d_in[1];
    const float* W1   = (const float*)d_in[2];
    const float* b1   = (const float*)d_in[3];
    const float* W2   = (const float*)d_in[4];
    const float* b2   = (const float*)d_in[5];
    const float* temp = (const float*)d_in[6];

    int N = in_sizes[0] / 512;
    int E = in_sizes[1] / 2;
    const int* src = ei;
    const int* dst = ei + E;
    float* out = (float*)d_out;

    int ntiles = (N + 63) / 64;

    char* w = (char*)d_ws;
    auto alloc = [&](size_t bytes) {
        char* p = w;
        w += (bytes + 255) & ~(size_t)255;
        return p;
    };
    float* acoef  = (float*)alloc(64);
    int*   flags  = (int*)alloc(64);
    int*   degs   = (int*)alloc((size_t)N * 4);
    int*   degd   = (int*)alloc((size_t)N * 4);
    int*   cursor = (int*)alloc((size_t)N * 4);
    int*   rowp   = (int*)alloc((size_t)(N + 1) * 4);
    float* dis    = (float*)alloc((size_t)N * 4);
    int*   csrs   = (int*)alloc((size_t)E * 4);
    float* csrw   = (float*)alloc((size_t)E * 4);
    ushort* w1b   = (ushort*)alloc(512 * 256 * 2);
    ushort* w2h   = (ushort*)alloc(256 * 64 * 2);
    ushort* w2l   = (ushort*)alloc(256 * 64 * 2);
    ushort* h1g   = (ushort*)alloc((size_t)ntiles * 32768);
    float* v0     = (float*)alloc((size_t)N * 64 * 4);
    float* v1     = (float*)alloc((size_t)N * 64 * 4);

    hipMemsetAsync(degs, 0, (size_t)N * 4, stream);
    hipMemsetAsync(degd, 0, (size_t)N * 4, stream);
    hipMemsetAsync(cursor, 0, (size_t)N * 4, stream);

    coef_kernel<<<1, 64, 0, stream>>>(temp, acoef, flags);
    prep_kernel<<<576, 256, 0, stream>>>(W1, W2, w1b, w2h, w2l);

    count_kernel<<<2048, 256, 0, stream>>>(src, dst, degs, degd, E, flags);
    scan_kernel<<<1, 1024, 0, stream>>>(degd, rowp, N, flags);
    dis_kernel<<<512, 256, 0, stream>>>(degs, dis, N, flags);
    fill_kernel<<<2048, 256, 0, stream>>>(src, dst, rowp, cursor, dis, csrs, csrw, E, flags);

    gemm1_kernel<<<ntiles, 256, 0, stream>>>(x, w1b, b1, h1g, N);
    gemm2_kernel<<<ntiles, 256, 0, stream>>>(h1g, w2h, w2l, b2, v0, out, acoef, flags, N);

    float* va = v0;
    float* vb = v1;
    for (int j = 1; j <= KORD; ++j) {
        adj_kernel<<<2048, 256, 0, stream>>>(rowp, csrs, csrw, va, vb, out,
                                             acoef, flags, j, N);
        float* tswap = va; va = vb; vb = tswap;
    }

    lsm_kernel<<<2048, 256, 0, stream>>>(out, N, flags);
}

// Round 6
// 101.061 us; speedup vs baseline: 5.6620x; 1.4615x over previous
//
#include <hip/hip_runtime.h>
#include <hip/hip_bf16.h>
#include <hip/hip_cooperative_groups.h>
#include <math.h>

// ---------------------------------------------------------------------------
// BernNet: out = log_softmax( bern_prop( relu(x@W1+b1)@W2+b2 ) )
// bern_prop in monomial basis: out = sum_j a_j A^j v0 (10 matvecs, not 65);
// trailing-zero coefficient fast path: all graph work lives in ONE cooperative
// kernel that returns immediately when a_j==0 for all j>=1 (log_softmax is
// then fused into the MLP epilogue).
// MLP fused into one kernel: phase1 x@W1 (bf16 MFMA, W1 pre-arranged
// fragment-linear in global, x double-buffered through LDS), h1 kept in LDS,
// phase2 h1@W2 (split hi/lo bf16 for fp32-grade W2 accuracy).
// ---------------------------------------------------------------------------

#define KORD 10

namespace cg = cooperative_groups;

typedef __attribute__((ext_vector_type(8))) short bf16x8;
typedef __attribute__((ext_vector_type(4))) float f32x4;

typedef __attribute__((address_space(1))) const unsigned int* gas_t;
typedef __attribute__((address_space(3))) unsigned int* las_t;

static __device__ __forceinline__ void gll16(const void* g, void* l) {
    // per-lane global addr g; wave-uniform LDS base l; writes l + lane*16
    __builtin_amdgcn_global_load_lds((gas_t)g, (las_t)l, 16, 0, 0);
}

static __device__ __forceinline__ ushort f2bf(float f) {   // RNE
    unsigned u = __float_as_uint(f);
    unsigned r = (u + 0x7fffu + ((u >> 16) & 1u)) >> 16;
    return (ushort)r;
}
static __device__ __forceinline__ float bf2f(ushort h) {
    return __uint_as_float(((unsigned)h) << 16);
}
static __device__ __forceinline__ uint pack2(float a, float b) {
    return (uint)f2bf(a) | ((uint)f2bf(b) << 16);
}

// ---- one-time setup: monomial coeffs + weight conversion -------------------
// W1 -> fragment-linear bf16: idx = kt*8192 + col*32 + lg*8 + j  (k=kt*32+lg*8+j)
// W2 -> hi/lo bf16:           idx = ks*2048 + col*32 + lg*8 + j  (k=ks*32+lg*8+j)
__global__ void prep_all(const float* __restrict__ temp,
                         const float* __restrict__ W1, const float* __restrict__ W2,
                         float* __restrict__ acoef, int* __restrict__ flags,
                         ushort* __restrict__ w1b,
                         ushort* __restrict__ w2h, ushort* __restrict__ w2l)
{
    int tid = blockIdx.x * 256 + threadIdx.x;
    if (tid == 0) {
        int C[KORD + 1][KORD + 1];
        for (int n = 0; n <= KORD; ++n) {
            for (int k = 0; k <= KORD; ++k) C[n][k] = 0;
            C[n][0] = 1;
            for (int k = 1; k <= n; ++k)
                C[n][k] = C[n - 1][k - 1] + ((k <= n - 1) ? C[n - 1][k] : 0);
        }
        float a[KORD + 1];
        for (int j = 0; j <= KORD; ++j) a[j] = 0.f;
        for (int m = 0; m <= KORD; ++m) {
            float tm = temp[m];
            tm = tm > 0.f ? tm : 0.f;
            float cm = (float)C[KORD][m] / 1024.0f;
            for (int p = 0; p <= m; ++p)
                for (int q = 0; q <= KORD - m; ++q) {
                    int Mij = ((p & 1) ? -1 : 1) * C[m][p] * C[KORD - m][q];
                    a[p + q] += cm * tm * (float)Mij;
                }
        }
        for (int j = 0; j <= KORD; ++j) acoef[j] = a[j];
        int any = 0;
        for (int j = KORD; j >= 0; --j) {
            if (a[j] != 0.f) any = 1;
            flags[j] = any;
        }
    }
    if (tid < 512 * 256) {
        int j = tid & 7, lg = (tid >> 3) & 3, col = (tid >> 5) & 255, kt = tid >> 13;
        int k = kt * 32 + lg * 8 + j;
        w1b[tid] = f2bf(W1[k * 256 + col]);
    } else if (tid < 512 * 256 + 256 * 64) {
        int t2 = tid - 512 * 256;
        int j = t2 & 7, lg = (t2 >> 3) & 3, col = (t2 >> 5) & 63, ks = t2 >> 11;
        int k = ks * 32 + lg * 8 + j;
        float v = W2[k * 64 + col];
        ushort hi = f2bf(v);
        ushort lo = f2bf(v - bf2f(hi));
        w2h[t2] = hi; w2l[t2] = lo;
    }
}

// ---- fused MLP: v0 = relu(x@W1+b1)@W2+b2 ; out = a0*v0 (or lsm(v0)) -------
// 512 thr / 8 waves; tile 128 rows x 256 cols; phase1 waves 2x4 (64x64/wave);
// phase2: 16 rows/wave x 64 cols, K=256 from the LDS h1 image.
__global__ __launch_bounds__(512, 4) void mlp_kernel(
    const float* __restrict__ x,
    const ushort* __restrict__ w1b,
    const ushort* __restrict__ w2h, const ushort* __restrict__ w2l,
    const float* __restrict__ b1, const float* __restrict__ b2,
    float* __restrict__ v0, float* __restrict__ out,
    const float* __restrict__ acoef, const int* __restrict__ flags, int N)
{
    __shared__ __align__(16) char sm[65536];
    // [0:8K) xb0, [8K:16K) xb1, [16K:32K) bb0, [32K:48K) bb1; h1 image [0:64K)

    const int t    = threadIdx.x;
    const int lane = t & 63;
    const int wid  = t >> 6;        // 0..7
    const int wm   = wid >> 2;      // 0..1 (row half)
    const int wn   = wid & 3;       // 0..3 (col quarter)
    const int l15  = lane & 15;
    const int lg   = lane >> 4;
    const int tile = blockIdx.x;
    const int row0 = tile * 128;

    f32x4 acc[4][4];
#pragma unroll
    for (int i = 0; i < 4; ++i)
#pragma unroll
        for (int j = 0; j < 4; ++j) acc[i][j] = (f32x4)0.f;

    // x staging: thread -> (local row sr = t>>2, 8-elem quad sq = t&3)
    const int sr = t >> 2;          // 0..127
    const int sq = t & 3;
    int rl = row0 + sr; if (rl > N - 1) rl = N - 1;       // clamp (no OOB)
    const float* xsrc = x + (size_t)rl * 512 + sq * 8;
    ushort* xb0 = (ushort*)sm;
    ushort* xb1 = (ushort*)(sm + 8192);
    uint4* xdst0 = (uint4*)(sm + t * 16);                 // frag-linear: idx8 == t
    uint4* xdst1 = (uint4*)(sm + 8192 + t * 16);

    const char* w1base = (const char*)w1b;
    char* bb0 = sm + 16384;
    char* bb1 = sm + 32768;

    // ---- prologue ----
    float4 xa0 = *(const float4*)(xsrc);
    float4 xa1 = *(const float4*)(xsrc + 4);
#pragma unroll
    for (int i = 0; i < 2; ++i)
        gll16(w1base + (size_t)wid * 2048 + i * 1024 + lane * 16,
              bb0 + wid * 2048 + i * 1024);
    float4 xc0 = *(const float4*)(xsrc + 32);
    float4 xc1 = *(const float4*)(xsrc + 36);
    *xdst0 = make_uint4(pack2(xa0.x, xa0.y), pack2(xa0.z, xa0.w),
                        pack2(xa1.x, xa1.y), pack2(xa1.z, xa1.w));
    __syncthreads();

    for (int kt2 = 0; kt2 < 16; kt2 += 2) {
        // ===== sub-iter A: kt = kt2 (cur: xb0/bb0) =====
        {
            int ktn = kt2 + 1;                            // stage W1(kt+1)
#pragma unroll
            for (int i = 0; i < 2; ++i)
                gll16(w1base + (size_t)ktn * 16384 + wid * 2048 + i * 1024 + lane * 16,
                      bb1 + wid * 2048 + i * 1024);
            int ktx = kt2 + 2; if (ktx > 15) ktx = 15;    // x prefetch depth 2
            xa0 = *(const float4*)(xsrc + ktx * 32);
            xa1 = *(const float4*)(xsrc + ktx * 32 + 4);

            bf16x8 Ah[4];
#pragma unroll
            for (int mf = 0; mf < 4; ++mf)
                Ah[mf] = *(const bf16x8*)&xb0[((wm * 4 + mf) * 64 + l15 * 4 + lg) * 8];
#pragma unroll
            for (int nf = 0; nf < 4; ++nf) {
                bf16x8 B = *(const bf16x8*)(bb0 + (wn * 64 + nf * 16 + l15) * 64 + lg * 16);
#pragma unroll
                for (int mf = 0; mf < 4; ++mf)
                    acc[mf][nf] = __builtin_amdgcn_mfma_f32_16x16x32_bf16(Ah[mf], B, acc[mf][nf], 0, 0, 0);
            }
            *xdst1 = make_uint4(pack2(xc0.x, xc0.y), pack2(xc0.z, xc0.w),
                                pack2(xc1.x, xc1.y), pack2(xc1.z, xc1.w));
            __syncthreads();
        }
        // ===== sub-iter B: kt = kt2+1 (cur: xb1/bb1) =====
        {
            int ktn = kt2 + 2; if (ktn > 15) ktn = 15;    // stage W1(kt+2)
#pragma unroll
            for (int i = 0; i < 2; ++i)
                gll16(w1base + (size_t)ktn * 16384 + wid * 2048 + i * 1024 + lane * 16,
                      bb0 + wid * 2048 + i * 1024);
            int ktx = kt2 + 3; if (ktx > 15) ktx = 15;
            xc0 = *(const float4*)(xsrc + ktx * 32);
            xc1 = *(const float4*)(xsrc + ktx * 32 + 4);

            bf16x8 Ah[4];
#pragma unroll
            for (int mf = 0; mf < 4; ++mf)
                Ah[mf] = *(const bf16x8*)&xb1[((wm * 4 + mf) * 64 + l15 * 4 + lg) * 8];
#pragma unroll
            for (int nf = 0; nf < 4; ++nf) {
                bf16x8 B = *(const bf16x8*)(bb1 + (wn * 64 + nf * 16 + l15) * 64 + lg * 16);
#pragma unroll
                for (int mf = 0; mf < 4; ++mf)
                    acc[mf][nf] = __builtin_amdgcn_mfma_f32_16x16x32_bf16(Ah[mf], B, acc[mf][nf], 0, 0, 0);
            }
            *xdst0 = make_uint4(pack2(xa0.x, xa0.y), pack2(xa0.z, xa0.w),
                                pack2(xa1.x, xa1.y), pack2(xa1.z, xa1.w));
            __syncthreads();
        }
    }

    // ---- h1 = relu(acc+b1) -> bf16 -> LDS frag-linear image [0:64K) ----
    ushort* h1l = (ushort*)sm;
#pragma unroll
    for (int nf = 0; nf < 4; ++nf) {
        int col = wn * 64 + nf * 16 + l15;
        float bb = b1[col];
        int ks = col >> 5, lgw = (col >> 3) & 3, j = col & 7;
#pragma unroll
        for (int mf = 0; mf < 4; ++mf) {
            int g = wm * 4 + mf;
#pragma unroll
            for (int r = 0; r < 4; ++r) {
                float v = acc[mf][nf][r] + bb;
                v = fmaxf(v, 0.f);
                int l15w = lg * 4 + r;
                h1l[(((ks * 8 + g) * 64) + l15w * 4 + lgw) * 8 + j] = f2bf(v);
            }
        }
    }
    __syncthreads();

    // ---- phase 2: rows wid*16..+15, 64 cols, K=256 from LDS image ----
    f32x4 acc2[4];
#pragma unroll
    for (int i = 0; i < 4; ++i) acc2[i] = (f32x4)0.f;
#pragma unroll
    for (int ks = 0; ks < 8; ++ks) {
        bf16x8 A = *(const bf16x8*)&h1l[((ks * 8 + wid) * 64 + l15 * 4 + lg) * 8];
#pragma unroll
        for (int nf = 0; nf < 4; ++nf) {
            size_t bo = (size_t)ks * 2048 + (nf * 16 + l15) * 32 + (lg << 3);
            bf16x8 Bh = *(const bf16x8*)(w2h + bo);
            bf16x8 Bl = *(const bf16x8*)(w2l + bo);
            acc2[nf] = __builtin_amdgcn_mfma_f32_16x16x32_bf16(A, Bh, acc2[nf], 0, 0, 0);
            acc2[nf] = __builtin_amdgcn_mfma_f32_16x16x32_bf16(A, Bl, acc2[nf], 0, 0, 0);
        }
    }

    // ---- epilogue ----
    int flag1 = flags[0 + 1];
    float a0c = acoef[0];
    float z[4][4];
#pragma unroll
    for (int nf = 0; nf < 4; ++nf) {
        float bb = b2[nf * 16 + l15];
#pragma unroll
        for (int r = 0; r < 4; ++r) z[nf][r] = acc2[nf][r] + bb;
    }
    if (!flag1) {
        // fused log_softmax: the 16 l15-lanes of this lg group share 4 rows
#pragma unroll
        for (int r = 0; r < 4; ++r) {
            int row = row0 + wid * 16 + lg * 4 + r;
            float mx = fmaxf(fmaxf(z[0][r], z[1][r]), fmaxf(z[2][r], z[3][r]));
#pragma unroll
            for (int off = 1; off < 16; off <<= 1) mx = fmaxf(mx, __shfl_xor(mx, off, 64));
            float s = expf(z[0][r] - mx) + expf(z[1][r] - mx)
                    + expf(z[2][r] - mx) + expf(z[3][r] - mx);
#pragma unroll
            for (int off = 1; off < 16; off <<= 1) s += __shfl_xor(s, off, 64);
            float lns = logf(s);
            if (row < N) {
#pragma unroll
                for (int nf = 0; nf < 4; ++nf)
                    out[(size_t)row * 64 + nf * 16 + l15] = z[nf][r] - mx - lns;
            }
        }
    } else {
#pragma unroll
        for (int nf = 0; nf < 4; ++nf) {
            int col = nf * 16 + l15;
#pragma unroll
            for (int r = 0; r < 4; ++r) {
                int row = row0 + wid * 16 + lg * 4 + r;
                if (row < N) {
                    size_t o = (size_t)row * 64 + col;
                    v0[o] = z[nf][r];
                    out[o] = a0c * z[nf][r];
                }
            }
        }
    }
}

// ---- all graph work in one cooperative kernel (active path only) ----------
__global__ __launch_bounds__(256) void graph_coop(
    const int* __restrict__ src, const int* __restrict__ dst, int E, int N,
    int* __restrict__ degs, int* __restrict__ degd, int* __restrict__ cursor,
    int* __restrict__ rowp, int* __restrict__ csrs, float* __restrict__ csrw,
    float* __restrict__ v0, float* __restrict__ v1, float* __restrict__ out,
    const float* __restrict__ acoef, const int* __restrict__ flags)
{
    __shared__ int sums[256];
    if (!flags[1]) return;                  // uniform early-out: no syncs occur
    cg::grid_group grid = cg::this_grid();
    int gtid = blockIdx.x * 256 + threadIdx.x;
    int gstr = gridDim.x * 256;

    // phase 0: zero
    for (int i = gtid; i < N; i += gstr) { degs[i] = 0; degd[i] = 0; cursor[i] = 0; }
    grid.sync();
    // phase 1: degree count
    for (int e = gtid; e < E; e += gstr) {
        atomicAdd(&degs[src[e]], 1);
        atomicAdd(&degd[dst[e]], 1);
    }
    grid.sync();
    // phase 2: exclusive prefix over degd -> rowp (block 0)
    if (blockIdx.x == 0) {
        int tid = threadIdx.x;
        int chunk = (N + 255) / 256;
        int s0 = tid * chunk;
        int s1 = s0 + chunk; if (s1 > N) s1 = N; if (s0 > N) s0 = N;
        int s = 0;
        for (int i = s0; i < s1; ++i) s += degd[i];
        sums[tid] = s;
        __syncthreads();
        for (int off = 1; off < 256; off <<= 1) {
            int v = (tid >= off) ? sums[tid - off] : 0;
            __syncthreads();
            sums[tid] += v;
            __syncthreads();
        }
        int run = sums[tid] - s;
        for (int i = s0; i < s1; ++i) { rowp[i] = run; run += degd[i]; }
        if (tid == 255) rowp[N] = sums[255];
    }
    grid.sync();
    // phase 3: CSR fill (sym-norm weight computed on the fly from degs)
    for (int e = gtid; e < E; e += gstr) {
        int s = src[e], d = dst[e];
        int dgs = degs[s], dgd = degs[d];
        float ws_ = (dgs > 0 ? rsqrtf((float)dgs) : 0.f)
                  * (dgd > 0 ? rsqrtf((float)dgd) : 0.f);
        int slot = rowp[d] + atomicAdd(&cursor[d], 1);
        csrs[slot] = s;
        csrw[slot] = ws_;
    }
    grid.sync();
    // phase 4: out += a_j * A^j v0, j = 1..K
    const float* va = v0;
    float* vb = v1;
    int lane = threadIdx.x & 63;
    int grpbase = lane & 48;
    for (int j = 1; j <= KORD; ++j) {
        if (!flags[j]) break;               // uniform
        float aj = acoef[j];
        for (int idx = gtid; idx < N * 16; idx += gstr) {
            int n = idx >> 4;
            int q = idx & 15;
            int beg = rowp[n], end = rowp[n + 1];
            float4 acc = make_float4(0.f, 0.f, 0.f, 0.f);
            for (int base = beg; base < end; base += 16) {
                int s = 0; float wvv = 0.f;
                int ii = base + q;
                if (ii < end) { s = csrs[ii]; wvv = csrw[ii]; }
                int m = end - base; if (m > 16) m = 16;
                for (int u = 0; u < m; ++u) {
                    int ss = __shfl(s, grpbase + u, 64);
                    float ww = __shfl(wvv, grpbase + u, 64);
                    float4 vv = *(const float4*)(va + ((long)ss << 6) + (q << 2));
                    acc.x += ww * vv.x; acc.y += ww * vv.y;
                    acc.z += ww * vv.z; acc.w += ww * vv.w;
                }
            }
            long o = ((long)n << 6) + (q << 2);
            *(float4*)(vb + o) = acc;
            float4 ov = *(const float4*)(out + o);
            ov.x += aj * acc.x; ov.y += aj * acc.y;
            ov.z += aj * acc.z; ov.w += aj * acc.w;
            *(float4*)(out + o) = ov;
        }
        grid.sync();
        float* tsw = vb; vb = (float*)va; va = tsw;
    }
    // phase 5: log_softmax
    for (int idx = gtid; idx < N * 64; idx += gstr) {
        int n = idx >> 6;
        int c = idx & 63;
        float v = out[(long)n * 64 + c];
        float mx = v;
#pragma unroll
        for (int off = 32; off; off >>= 1) mx = fmaxf(mx, __shfl_xor(mx, off, 64));
        float e = expf(v - mx);
        float s = e;
#pragma unroll
        for (int off = 32; off; off >>= 1) s += __shfl_xor(s, off, 64);
        out[(long)n * 64 + c] = v - mx - logf(s);
    }
}

extern "C" void kernel_launch(void* const* d_in, const int* in_sizes, int n_in,
                              void* d_out, int out_size, void* d_ws, size_t ws_size,
                              hipStream_t stream)
{
    const float* x    = (const float*)d_in[0];
    const int*   ei   = (const int*)d_in[1];
    const float* W1   = (const float*)d_in[2];
    const float* b1   = (const float*)d_in[3];
    const float* W2   = (const float*)d_in[4];
    const float* b2   = (const float*)d_in[5];
    const float* temp = (const float*)d_in[6];

    int N = in_sizes[0] / 512;
    int E = in_sizes[1] / 2;
    const int* src = ei;
    const int* dst = ei + E;
    float* out = (float*)d_out;

    char* w = (char*)d_ws;
    auto alloc = [&](size_t bytes) {
        char* p = w;
        w += (bytes + 255) & ~(size_t)255;
        return p;
    };
    float* acoef  = (float*)alloc(64);
    int*   flags  = (int*)alloc(64);
    int*   degs   = (int*)alloc((size_t)N * 4);
    int*   degd   = (int*)alloc((size_t)N * 4);
    int*   cursor = (int*)alloc((size_t)N * 4);
    int*   rowp   = (int*)alloc((size_t)(N + 1) * 4);
    int*   csrs   = (int*)alloc((size_t)E * 4);
    float* csrw   = (float*)alloc((size_t)E * 4);
    ushort* w1b   = (ushort*)alloc(512 * 256 * 2);
    ushort* w2h   = (ushort*)alloc(256 * 64 * 2);
    ushort* w2l   = (ushort*)alloc(256 * 64 * 2);
    float* v0     = (float*)alloc((size_t)N * 64 * 4);
    float* v1     = (float*)alloc((size_t)N * 64 * 4);

    prep_all<<<576, 256, 0, stream>>>(temp, W1, W2, acoef, flags, w1b, w2h, w2l);

    int ntiles = (N + 127) / 128;
    mlp_kernel<<<ntiles, 512, 0, stream>>>(x, w1b, w2h, w2l, b1, b2, v0, out,
                                           acoef, flags, N);

    int Ei = E, Ni = N;
    void* cargs[] = {
        (void*)&src, (void*)&dst, (void*)&Ei, (void*)&Ni,
        (void*)&degs, (void*)&degd, (void*)&cursor, (void*)&rowp,
        (void*)&csrs, (void*)&csrw, (void*)&v0, (void*)&v1, (void*)&out,
        (void*)&acoef, (void*)&flags
    };
    hipLaunchCooperativeKernel((void*)graph_coop, dim3(1024), dim3(256),
                               cargs, 0, stream);
}